// Round 8
// baseline (261.136 us; speedup 1.0000x reference)
//
#include <hip/hip_runtime.h>
#include <math.h>

// CrossViewSwapAttention forward. Round 19: T14 everywhere.
// R18 base (240.9us). (a) conv path: W1 projection weight loads issued in P0
// (hide under feat staging), written from regs in P2; W2 loads issued at
// GEMM1 start (hide under MFMAs), written from regs in P9. (b) k_attn2:
// 1-deep Q-fragment prefetch pipeline across the camera loop (cam0 load
// hides under K/V staging; cam+1 under the MFMA/exp chain). All values and
// rounding points bit-identical to R18.
// B=2 N=6 H=W=64 FH=32 FW=88 DIM=128 HEADS=4 DH=32 QW=8x8 KW=4x11

typedef __attribute__((ext_vector_type(8))) short short8;
typedef __attribute__((ext_vector_type(4))) float f32x4;

__device__ __forceinline__ unsigned short f2bf(float f){
  union { float f; unsigned u; } v; v.f = f;
  unsigned r = v.u + 0x7FFF + ((v.u >> 16) & 1);   // RNE
  return (unsigned short)(r >> 16);
}
__device__ __forceinline__ float bf2f(unsigned short h){
  union { unsigned u; float f; } v; v.u = ((unsigned)h) << 16; return v.f;
}
__device__ __forceinline__ void store_bf16x8(unsigned short* p, const float* v){
  union { short8 s8; unsigned short u[8]; } u;
  #pragma unroll
  for (int i=0;i<8;i++) u.u[i] = f2bf(v[i]);
  *(short8*)p = u.s8;
}

__device__ __forceinline__ float gelu_erf(float x){
  float z = x * 0.70710678118654752f;
  float a = fabsf(z);
  float t = 1.0f / fmaf(0.3275911f, a, 1.0f);
  float p = t*(0.254829592f + t*(-0.284496736f + t*(1.421413741f +
            t*(-1.453152027f + t*1.061405429f))));
  float er = 1.0f - p*__expf(-a*a);
  er = copysignf(er, z);
  return 0.5f * x * (1.0f + er);
}

__device__ __forceinline__ size_t remap_kv(int tok, int mode){
  int bn = tok / 2816; int p = tok - bn*2816;
  int b = bn / 6, n = bn - b*6;
  int i = p / 88, j = p - i*88;
  int l, t;
  if (mode == 1){
    int jw = j / 11;
    l = (i >> 2)*8 + jw;
    t = n*44 + (i & 3)*11 + (j - jw*11);
  } else {
    l = (i & 7)*8 + (j & 7);
    t = n*44 + (i >> 3)*11 + (j >> 3);
  }
  return (size_t)((b*64 + l)*264 + t);
}

// == fused dispatch 1: conv(+geom+LN+dual KV proj) | bevq(+Q1) | wprep | bias
// grid: [0,528) conv, [528,1040) bevq, [1040,1076) wprep, [1076,1077) bias3
__global__ __launch_bounds__(256) void k_prepconv(
    const float* __restrict__ qkv, const float* __restrict__ wp,
    const float* __restrict__ wma, const float* __restrict__ wmb,
    unsigned short* __restrict__ Wt,
    const float* __restrict__ abqkv, float* __restrict__ biasP,
    const float* __restrict__ gridp, const float* __restrict__ Wbev,
    const float* __restrict__ bbev, const float* __restrict__ x,
    const float* __restrict__ lg, const float* __restrict__ lb,
    const float* __restrict__ Einv, const float* __restrict__ Wcam,
    unsigned short* __restrict__ QPh,
    const float* __restrict__ feat,
    const float* __restrict__ gfp, const float* __restrict__ bfp,
    const float* __restrict__ Wfp,
    const float* __restrict__ gfl, const float* __restrict__ bfl,
    const float* __restrict__ Wfl,
    const float* __restrict__ Iinv, const float* __restrict__ Wimg,
    unsigned short* __restrict__ KPh, unsigned short* __restrict__ KP2h,
    unsigned short* __restrict__ VPh, unsigned short* __restrict__ VP2h){
  constexpr int KP_ = 136;
  __shared__ unsigned short sW[128*KP_];
  __shared__ unsigned short sA[128*KP_];
  __shared__ __align__(16) float sMisc[2560];
  const int bid = blockIdx.x;
  const int tid = threadIdx.x;

  if (bid < 528){
    float* sg_  = sMisc;
    float* sb_  = sMisc + 128;
    float* sMean= sMisc + 256;
    float* sRstd= sMisc + 384;
    float* sRn  = sMisc + 512;
    float* sCE  = sMisc + 640;
    float4* sWI4= (float4*)(sMisc + 768);
    float* sIE  = sMisc + 1280;
    float* sB1  = sMisc + 1312;
    float* sB2  = sMisc + 1440;
    const int which = (bid >= 264);
    const int cbid = which ? bid - 264 : bid;
    const int m1 = which ? 2 : 1;
    const int m2 = which ? 5 : 4;
    const float* gg = which ? gfl : gfp;
    const float* bb = which ? bfl : bfp;
    const float* Wf = which ? Wfl : Wfp;
    unsigned short* Oa = which ? VPh : KPh;
    unsigned short* Ob = which ? VP2h : KP2h;
    const int base = cbid * 128;
    const int bn = base / 2816;
    const int pbase = base - bn*2816;
    if (tid < 128){ sg_[tid]=gg[tid]; sb_[tid]=bb[tid]; }
    if (!which){
      if (tid < 128){
        const float* E = Einv + bn*16;
        float4 wc = *(const float4*)(Wcam + tid*4);
        sCE[tid] = wc.x*E[3] + wc.y*E[7] + wc.z*E[11] + wc.w*E[15];
        sWI4[tid] = *(const float4*)(Wimg + tid*4);
      }
      if (tid < 25) sIE[tid] = (tid < 9) ? Iinv[bn*9 + tid] : Einv[bn*16 + (tid-9)];
    }
    for (int i = tid; i < 2048; i += 256){
      int n = i >> 4, k8 = (i & 15) << 3;
      const float* wsp = Wf + (size_t)n*128 + k8;
      float4 f0 = *(const float4*)wsp;
      float4 f1 = *(const float4*)(wsp+4);
      float v8[8] = {f0.x,f0.y,f0.z,f0.w,f1.x,f1.y,f1.z,f1.w};
      store_bf16x8(&sW[n*KP_ + k8], v8);
    }
    {
      int n = tid & 127, wsel = tid >> 7;
      int m = wsel ? m2 : m1;
      const float* W = qkv + m*16384;
      const float* lnb = lb + m*128;
      float s = abqkv[m*128 + n];
      for (int k=0;k<128;k++) s = fmaf(lnb[k], W[k*128 + n], s);
      (wsel ? sB2 : sB1)[n] = s;
    }
    const float RSQ = rsqrtf(1.0f + 1e-5f);
    {
      int prow = tid & 127, cseg = tid >> 7;
      int p = pbase + prow;
      const float* fb = feat + ((size_t)bn*128 + cseg*64)*2816 + p;
      #pragma unroll 8
      for (int i=0;i<64;i+=2){
        int c = cseg*64 + i;
        float t0 = fb[(size_t)i*2816] * RSQ;
        float t1 = fb[(size_t)(i+1)*2816] * RSQ;
        float y0 = fmaxf(fmaf(t0, sg_[c],   sb_[c]),   0.f);
        float y1 = fmaxf(fmaf(t1, sg_[c+1], sb_[c+1]), 0.f);
        unsigned u = (unsigned)f2bf(y0) | ((unsigned)f2bf(y1) << 16);
        *(unsigned*)&sA[prow*KP_ + c] = u;
      }
    }
    // T14: issue W1 projection-weight loads now (hide under feat staging /
    // complete at the barrier); fold+write happens from regs in P2.
    float w1reg[64];
    {
      const float* Wsrc = qkv + m1*16384;
      #pragma unroll
      for (int i=0;i<32;i++){
        int idx = tid + i*256;
        int n = idx & 127, k2 = (idx >> 7) << 1;
        w1reg[2*i]   = Wsrc[(size_t)k2*128 + n];
        w1reg[2*i+1] = Wsrc[(size_t)(k2+1)*128 + n];
      }
    }
    __syncthreads();
    const int lane = tid & 63, wv = tid >> 6;
    const int lane15 = lane & 15, quad = lane >> 4;
    const int n0 = wv * 32;
    const unsigned short* aptr = sA + lane15*KP_ + quad*8;
    const unsigned short* bptr = sW + (size_t)(n0 + lane15)*KP_ + quad*8;
    f32x4 acc[8][2];
    // P1: conv MFMA
    #pragma unroll
    for (int mt=0; mt<8; mt++){ acc[mt][0]=(f32x4)0.f; acc[mt][1]=(f32x4)0.f; }
    #pragma unroll
    for (int kk=0; kk<4; kk++){
      short8 af[8], bf2v[2];
      #pragma unroll
      for (int mt=0; mt<8; mt++) af[mt] = *(const short8*)(aptr + mt*16*KP_ + kk*32);
      bf2v[0] = *(const short8*)(bptr + kk*32);
      bf2v[1] = *(const short8*)(bptr + 16*KP_ + kk*32);
      #pragma unroll
      for (int mt=0; mt<8; mt++){
        acc[mt][0] = __builtin_amdgcn_mfma_f32_16x16x32_bf16(af[mt], bf2v[0], acc[mt][0], 0,0,0);
        acc[mt][1] = __builtin_amdgcn_mfma_f32_16x16x32_bf16(af[mt], bf2v[1], acc[mt][1], 0,0,0);
      }
    }
    __syncthreads();
    // P2: (K) geom -> sA + sRn; (all) write folded W1 from regs -> sW
    if (!which){
      const int r = tid >> 1, half = tid & 1;
      int p = pbase + r;
      int ii = p / 88, jj = p - ii*88;
      float xs = (float)jj * (480.0f/87.0f);
      float ys = (float)ii * (224.0f/31.0f);
      float c0 = sIE[0]*xs + sIE[1]*ys + sIE[2];
      float c1 = sIE[3]*xs + sIE[4]*ys + sIE[5];
      float c2 = sIE[6]*xs + sIE[7]*ys + sIE[8];
      float d0 = sIE[9]*c0  + sIE[10]*c1 + sIE[11]*c2 + sIE[12];
      float d1 = sIE[13]*c0 + sIE[14]*c1 + sIE[15]*c2 + sIE[16];
      float d2 = sIE[17]*c0 + sIE[18]*c1 + sIE[19]*c2 + sIE[20];
      float d3 = sIE[21]*c0 + sIE[22]*c1 + sIE[23]*c2 + sIE[24];
      float sq = 0.f;
      #pragma unroll 8
      for (int k=0;k<64;k++){
        int c = half*64 + k;
        float4 w = sWI4[c];
        float de = w.x*d0 + w.y*d1 + w.z*d2 + w.w*d3 - sCE[c];
        sA[r*KP_ + c] = f2bf(de);
        sq = fmaf(de, de, sq);
      }
      sq += __shfl_xor(sq, 1);
      if (half == 0) sRn[r] = 1.0f / fmaxf(sqrtf(sq), 1e-12f);
    }
    {
      const float* gvv = lg + m1*128;
      #pragma unroll
      for (int i=0;i<32;i++){
        int idx = tid + i*256;
        int n = idx & 127, k2 = (idx >> 7) << 1;
        float v0 = w1reg[2*i]   * gvv[k2];
        float v1 = w1reg[2*i+1] * gvv[k2+1];
        *(unsigned*)&sW[n*KP_ + k2] = (unsigned)f2bf(v0) | ((unsigned)f2bf(v1) << 16);
      }
    }
    __syncthreads();
    // P3: epilogue: conv acc (+ geom for K) -> sA bf16
    #pragma unroll
    for (int mt=0; mt<8; mt++){
      #pragma unroll
      for (int nt=0; nt<2; nt++){
        int col = n0 + nt*16 + lane15;
        #pragma unroll
        for (int r4=0; r4<4; r4++){
          int row = mt*16 + quad*4 + r4;
          float v = acc[mt][nt][r4];
          if (!which) v += bf2f(sA[row*KP_ + col]) * sRn[row];   // + geom
          sA[row*KP_ + col] = f2bf(v);
        }
      }
    }
    __syncthreads();
    // P4: row stats
    {
      int r = tid >> 1, part = tid & 1;
      float s=0.f, s2=0.f;
      #pragma unroll 8
      for (int k=0;k<64;k++){
        float v = bf2f(sA[r*KP_ + part*64 + k]);
        s += v; s2 = fmaf(v,v,s2);
      }
      s += __shfl_xor(s, 1); s2 += __shfl_xor(s2, 1);
      if (part == 0){
        float mean = s*(1.f/128.f);
        sMean[r] = mean;
        sRstd[r] = rsqrtf(fmaxf(s2*(1.f/128.f) - mean*mean, 0.f) + 1e-5f);
      }
    }
    __syncthreads();
    // P5: normalize in place
    for (int i = tid; i < 2048; i += 256){
      int row = i >> 4, seg = i & 15;
      float mean = sMean[row], rstd = sRstd[row];
      union { short8 s; unsigned short u[8]; } t;
      t.s = *(const short8*)&sA[row*KP_ + seg*8];
      float v[8];
      #pragma unroll
      for (int k=0;k<8;k++) v[k] = (bf2f(t.u[k]) - mean)*rstd;
      store_bf16x8(&sA[row*KP_ + seg*8], v);
    }
    __syncthreads();
    // P6: GEMM1 (z x W1); W2 loads issued first, hide under the MFMAs
    float w2reg[64];
    {
      const float* Wsrc = qkv + m2*16384;
      #pragma unroll
      for (int i=0;i<32;i++){
        int idx = tid + i*256;
        int n = idx & 127, k2 = (idx >> 7) << 1;
        w2reg[2*i]   = Wsrc[(size_t)k2*128 + n];
        w2reg[2*i+1] = Wsrc[(size_t)(k2+1)*128 + n];
      }
    }
    #pragma unroll
    for (int mt=0; mt<8; mt++){ acc[mt][0]=(f32x4)0.f; acc[mt][1]=(f32x4)0.f; }
    #pragma unroll
    for (int kk=0; kk<4; kk++){
      short8 af[8], bf2v[2];
      #pragma unroll
      for (int mt=0; mt<8; mt++) af[mt] = *(const short8*)(aptr + mt*16*KP_ + kk*32);
      bf2v[0] = *(const short8*)(bptr + kk*32);
      bf2v[1] = *(const short8*)(bptr + 16*KP_ + kk*32);
      #pragma unroll
      for (int mt=0; mt<8; mt++){
        acc[mt][0] = __builtin_amdgcn_mfma_f32_16x16x32_bf16(af[mt], bf2v[0], acc[mt][0], 0,0,0);
        acc[mt][1] = __builtin_amdgcn_mfma_f32_16x16x32_bf16(af[mt], bf2v[1], acc[mt][1], 0,0,0);
      }
    }
    __syncthreads();
    // P7: epi1 -> sW
    #pragma unroll
    for (int mt=0; mt<8; mt++){
      #pragma unroll
      for (int nt=0; nt<2; nt++){
        int col = n0 + nt*16 + lane15;
        float bsv = sB1[col];
        #pragma unroll
        for (int r4=0; r4<4; r4++){
          int row = mt*16 + quad*4 + r4;
          sW[row*KP_ + col] = f2bf(acc[mt][nt][r4] + bsv);
        }
      }
    }
    __syncthreads();
    // P8: flush mode1
    for (int i = tid; i < 2048; i += 256){
      int row = i >> 4, seg = i & 15;
      size_t orow = remap_kv(base + row, 1);
      *(short8*)(Oa + orow*128 + seg*8) = *(const short8*)&sW[row*KP_ + seg*8];
    }
    __syncthreads();
    // P9: write folded W2 from regs -> sW
    {
      const float* gvv = lg + m2*128;
      #pragma unroll
      for (int i=0;i<32;i++){
        int idx = tid + i*256;
        int n = idx & 127, k2 = (idx >> 7) << 1;
        float v0 = w2reg[2*i]   * gvv[k2];
        float v1 = w2reg[2*i+1] * gvv[k2+1];
        *(unsigned*)&sW[n*KP_ + k2] = (unsigned)f2bf(v0) | ((unsigned)f2bf(v1) << 16);
      }
    }
    __syncthreads();
    // P10: GEMM2 (z x W2)
    #pragma unroll
    for (int mt=0; mt<8; mt++){ acc[mt][0]=(f32x4)0.f; acc[mt][1]=(f32x4)0.f; }
    #pragma unroll
    for (int kk=0; kk<4; kk++){
      short8 af[8], bf2v[2];
      #pragma unroll
      for (int mt=0; mt<8; mt++) af[mt] = *(const short8*)(aptr + mt*16*KP_ + kk*32);
      bf2v[0] = *(const short8*)(bptr + kk*32);
      bf2v[1] = *(const short8*)(bptr + 16*KP_ + kk*32);
      #pragma unroll
      for (int mt=0; mt<8; mt++){
        acc[mt][0] = __builtin_amdgcn_mfma_f32_16x16x32_bf16(af[mt], bf2v[0], acc[mt][0], 0,0,0);
        acc[mt][1] = __builtin_amdgcn_mfma_f32_16x16x32_bf16(af[mt], bf2v[1], acc[mt][1], 0,0,0);
      }
    }
    __syncthreads();
    // P11: epi2 -> sA
    #pragma unroll
    for (int mt=0; mt<8; mt++){
      #pragma unroll
      for (int nt=0; nt<2; nt++){
        int col = n0 + nt*16 + lane15;
        float bsv = sB2[col];
        #pragma unroll
        for (int r4=0; r4<4; r4++){
          int row = mt*16 + quad*4 + r4;
          sA[row*KP_ + col] = f2bf(acc[mt][nt][r4] + bsv);
        }
      }
    }
    __syncthreads();
    // P12: flush mode2
    for (int i = tid; i < 2048; i += 256){
      int row = i >> 4, seg = i & 15;
      size_t orow = remap_kv(base + row, 2);
      *(short8*)(Ob + orow*128 + seg*8) = *(const short8*)&sA[row*KP_ + seg*8];
    }
  } else if (bid < 1040){
    // ---- bevq + fused Q1 projection -> QPh (16 pixels/block) ----
    const float QSCALE = 0.17677669529663687f;
    float* sx = sMisc;
    int* rowoff = (int*)(sMisc + 2176);
    int bid2 = bid - 528;
    int b = bid2 >> 8; int pp0 = (bid2 & 255) << 4;
    // self-stage Q1 weight, 2 bf16 per dword write
    for (int idx = tid; idx < 8192; idx += 256){
      int n = idx & 127, k2 = (idx >> 7) << 1;
      float v0 = qkv[(size_t)k2*128 + n];
      float v1 = qkv[(size_t)(k2+1)*128 + n];
      *(unsigned*)&sW[n*KP_ + k2] = (unsigned)f2bf(v0) | ((unsigned)f2bf(v1) << 16);
    }
    {
      int cg = tid >> 4, px = tid & 15;
      #pragma unroll
      for (int i=0;i<8;i++){
        int c = cg + 16*i;
        sx[c*17 + px] = x[(size_t)b*524288 + (size_t)c*4096 + pp0 + px];
      }
    }
    if (tid < 16){
      int pix = pp0 + tid; int h = pix >> 6, w = pix & 63;
      int l = (h>>3)*8 + (w>>3); int tq = (h&7)*8 + (w&7);
      rowoff[tid] = (b*64 + l)*384 + tq;
    }
    __syncthreads();
    int xid = tid >> 4, part = tid & 15;
    int pix = pp0 + xid;
    float g0 = gridp[pix], g1 = gridp[4096 + pix];
    float we[8], xv[8];
    #pragma unroll
    for (int k=0;k<8;k++){
      int o = part*8 + k;
      we[k] = Wbev[o*2]*g0 + Wbev[o*2+1]*g1 + bbev[o];
      xv[k] = sx[(part*8+k)*17 + xid];
    }
    for (int n=0; n<6; n++){
      const float* E = Einv + (b*6+n)*16;
      float v[8]; float sq = 0.f;
      #pragma unroll
      for (int k=0;k<8;k++){
        int o = part*8 + k;
        const float* Wc = Wcam + o*4;
        float ce = Wc[0]*E[3] + Wc[1]*E[7] + Wc[2]*E[11] + Wc[3]*E[15];
        float vv = we[k] - ce;
        v[k] = vv; sq = fmaf(vv, vv, sq);
      }
      #pragma unroll
      for (int off=8; off>0; off>>=1) sq += __shfl_xor(sq, off, 16);
      float rn = 1.0f / fmaxf(sqrtf(sq), 1e-12f);
      float q[8]; float s=0.f, s2=0.f;
      #pragma unroll
      for (int k=0;k<8;k++){
        q[k] = fmaf(v[k], rn, xv[k]);
        s += q[k]; s2 = fmaf(q[k], q[k], s2);
      }
      #pragma unroll
      for (int off=8; off>0; off>>=1){ s += __shfl_xor(s, off, 16); s2 += __shfl_xor(s2, off, 16); }
      float mean = s*(1.f/128.f);
      float rstd = rsqrtf(fmaxf(s2*(1.f/128.f) - mean*mean, 0.f) + 1e-5f);
      float o8[8];
      #pragma unroll
      for (int k=0;k<8;k++){
        int c = part*8 + k;
        o8[k] = fmaf((q[k]-mean)*rstd, lg[c], lb[c]);
      }
      store_bf16x8(sA + (size_t)(n*16 + xid)*KP_ + part*8, o8);
    }
    __syncthreads();
    const int lane = tid & 63, wv = tid >> 6;
    const int lane15 = lane & 15, quad = lane >> 4;
    const int n0 = wv * 32;
    f32x4 acc[6][2];
    #pragma unroll
    for (int mt=0; mt<6; mt++){ acc[mt][0]=(f32x4)0.f; acc[mt][1]=(f32x4)0.f; }
    const unsigned short* aptr = sA + lane15*KP_ + quad*8;
    const unsigned short* bptr = sW + (size_t)(n0 + lane15)*KP_ + quad*8;
    #pragma unroll
    for (int kk=0; kk<4; kk++){
      short8 af[6], bf2v[2];
      #pragma unroll
      for (int mt=0; mt<6; mt++) af[mt] = *(const short8*)(aptr + mt*16*KP_ + kk*32);
      bf2v[0] = *(const short8*)(bptr + kk*32);
      bf2v[1] = *(const short8*)(bptr + 16*KP_ + kk*32);
      #pragma unroll
      for (int mt=0; mt<6; mt++){
        acc[mt][0] = __builtin_amdgcn_mfma_f32_16x16x32_bf16(af[mt], bf2v[0], acc[mt][0], 0,0,0);
        acc[mt][1] = __builtin_amdgcn_mfma_f32_16x16x32_bf16(af[mt], bf2v[1], acc[mt][1], 0,0,0);
      }
    }
    __syncthreads();
    #pragma unroll
    for (int nt=0; nt<2; nt++){
      int col = n0 + nt*16 + lane15;
      float bsv = abqkv[col];
      #pragma unroll
      for (int mt=0; mt<6; mt++){
        #pragma unroll
        for (int r4=0; r4<4; r4++){
          int row = mt*16 + quad*4 + r4;
          sA[row*KP_ + col] = f2bf((acc[mt][nt][r4] + bsv) * QSCALE);
        }
      }
    }
    __syncthreads();
    for (int i = tid; i < 1536; i += 256){
      int r = i >> 4, seg = i & 15;
      size_t grow = (size_t)rowoff[r & 15] + (r >> 4)*64;
      *(short8*)(QPh + grow*128 + seg*8) = *(const short8*)&sA[r*KP_ + seg*8];
    }
  } else if (bid < 1076){
    const int sel[9]  = {0, 1,1, 2,2, 3,3,3,3};
    const int soff[9] = {49152, 0,16384, 0,32768, 0,16384,32768,49152};
    const int doff[9] = {49152, 98304,114688, 131072,163840,
                         196608,212992,229376,245760};
    const int Ns[9]   = {128, 128,128, 256,256, 128,128,128,128};
    int bidw = bid - 1040;
    int sg = bidw >> 2, q = bidw & 3;
    const float* srcs[4] = {qkv, wp, wma, wmb};
    const float* src = srcs[sel[sg]] + soff[sg];
    unsigned short* dst = Wt + doff[sg];
    int K = 128, N = Ns[sg];
    int quarter = (K*N) >> 2;
    bool fold = (sg == 0);
    const float* gv = lg + 384;
    for (int idx = q*quarter + tid; idx < (q+1)*quarter; idx += 256){
      int n = idx / K, k = idx - n*K;
      float v = src[k*N + n];
      if (fold) v *= gv[k];
      dst[idx] = f2bf(v);
    }
  } else {
    if (tid < 128){
      int n = tid;
      const float* lnb = lb + 384;
      const float* W = qkv + 49152;
      float s = abqkv[384 + n];
      for (int k=0;k<128;k++) s = fmaf(lnb[k], W[k*128 + n], s);
      biasP[384 + n] = s;
    }
  }
}

// ---------------- fused tail (T14 staged weights): P+skip+LN+MA+gelu+MB,
// then (stage1) q2-proj or (stage2) final LN + transposed store.
__global__ __launch_bounds__(256) void k_tail(
    const unsigned short* __restrict__ AOh,
    const float* __restrict__ skipf, int skipmode,
    const unsigned short* __restrict__ WtP, const float* __restrict__ abp,
    const float* __restrict__ png, const float* __restrict__ pnb,
    const unsigned short* __restrict__ WtMAa, const unsigned short* __restrict__ WtMAb,
    const float* __restrict__ bma,
    const unsigned short* __restrict__ WtMBa, const unsigned short* __restrict__ WtMBb,
    const float* __restrict__ bmb,
    float* __restrict__ Q1out,
    const unsigned short* __restrict__ WtQ2, const float* __restrict__ q2bias,
    float q2scale, unsigned short* __restrict__ QPout,
    const float* __restrict__ postg, const float* __restrict__ postb,
    float* __restrict__ out){
  constexpr int KP_ = 136;
  __shared__ unsigned short sW[128*KP_];
  __shared__ unsigned short sX[32*KP_];
  __shared__ unsigned short sH1[32*KP_];
  __shared__ unsigned short sH2[32*KP_];
  __shared__ float sCUR[32*132];
  __shared__ float sbias[128];
  __shared__ float sg[128], sb2[128];
  __shared__ float sMean[32], sRstd[32];
  const int tid = threadIdx.x;
  const int base = blockIdx.x * 32;
  const int lane = tid & 63, wv = tid >> 6;
  const int lane15 = lane & 15, quad = lane >> 4;
  const int n0 = wv * 32;

  short8 wreg[8];
  auto stageLoad = [&](const unsigned short* Wp){
    #pragma unroll
    for (int i=0;i<8;i++){
      int idx = tid + i*256;
      int n = idx >> 4, k8 = (idx & 15) << 3;
      wreg[i] = *(const short8*)(Wp + (size_t)n*128 + k8);
    }
  };
  auto stageWrite = [&](){
    #pragma unroll
    for (int i=0;i<8;i++){
      int idx = tid + i*256;
      int n = idx >> 4, k8 = (idx & 15) << 3;
      *(short8*)&sW[n*KP_ + k8] = wreg[i];
    }
  };
  auto domfma = [&](const unsigned short* Asrc, f32x4 acc[2][2]){
    const unsigned short* aptr = Asrc + lane15*KP_ + quad*8;
    const unsigned short* bptr = sW + (size_t)(n0 + lane15)*KP_ + quad*8;
    #pragma unroll
    for (int kk=0; kk<4; kk++){
      short8 a0 = *(const short8*)(aptr + kk*32);
      short8 a1 = *(const short8*)(aptr + 16*KP_ + kk*32);
      short8 b0 = *(const short8*)(bptr + kk*32);
      short8 b1 = *(const short8*)(bptr + 16*KP_ + kk*32);
      acc[0][0] = __builtin_amdgcn_mfma_f32_16x16x32_bf16(a0,b0,acc[0][0],0,0,0);
      acc[1][0] = __builtin_amdgcn_mfma_f32_16x16x32_bf16(a1,b0,acc[1][0],0,0,0);
      acc[0][1] = __builtin_amdgcn_mfma_f32_16x16x32_bf16(a0,b1,acc[0][1],0,0,0);
      acc[1][1] = __builtin_amdgcn_mfma_f32_16x16x32_bf16(a1,b1,acc[1][1],0,0,0);
    }
  };

  // phase 0: W_P staged; attn output -> sX
  stageLoad(WtP);
  {
    const int r = tid >> 3, part = tid & 7;
    const short8* src = (const short8*)(AOh + (size_t)(base+r)*128 + part*16);
    short8* dst = (short8*)(sX + r*KP_ + part*16);
    dst[0] = src[0]; dst[1] = src[1];
  }
  if (tid < 128){ sbias[tid] = abp[tid]; sg[tid] = png[tid]; sb2[tid] = pnb[tid]; }
  stageWrite();
  __syncthreads();
  // phase 1: GEMM_P (W_MAa loads in flight underneath)
  stageLoad(WtMAa);
  {
    f32x4 acc[2][2];
    acc[0][0]=(f32x4)0.f; acc[0][1]=(f32x4)0.f;
    acc[1][0]=(f32x4)0.f; acc[1][1]=(f32x4)0.f;
    domfma(sX, acc);
    #pragma unroll
    for (int mt=0; mt<2; mt++)
      #pragma unroll
      for (int nt=0; nt<2; nt++){
        int col = n0 + nt*16 + lane15;
        float bsv = sbias[col];
        #pragma unroll
        for (int r4=0; r4<4; r4++){
          int row = mt*16 + quad*4 + r4;
          int rrow = base + row;
          float v = acc[mt][nt][r4] + bsv;
          if (skipmode == 1){
            int bb = rrow >> 12, l = (rrow >> 6) & 63, pp = rrow & 63;
            int pix = (((l>>3)*8 + (pp>>3)) << 6) + (l&7)*8 + (pp&7);
            v += skipf[(size_t)bb*524288 + (size_t)col*4096 + pix];
          } else {
            v += skipf[(size_t)rrow*128 + col];
          }
          sCUR[row*132 + col] = v;
        }
      }
  }
  __syncthreads();
  // phase 2: write W_MAa; LN -> sX
  stageWrite();
  if (tid < 128) sbias[tid] = bma[tid];
  {
    const int r = tid >> 3, part = tid & 7;
    float v[16];
    #pragma unroll
    for (int k=0;k<16;k++) v[k] = sCUR[r*132 + part*16 + k];
    float s=0.f, s2=0.f;
    #pragma unroll
    for (int k=0;k<16;k++){ s += v[k]; s2 = fmaf(v[k],v[k],s2); }
    #pragma unroll
    for (int off=4; off>0; off>>=1){ s += __shfl_xor(s, off, 8); s2 += __shfl_xor(s2, off, 8); }
    float mean = s*(1.f/128.f);
    float rstd = rsqrtf(fmaxf(s2*(1.f/128.f) - mean*mean, 0.f) + 1e-5f);
    #pragma unroll
    for (int k=0;k<16;k++){
      int c = part*16 + k;
      v[k] = fmaf((v[k]-mean)*rstd, sg[c], sb2[c]);
    }
    store_bf16x8(sX + r*KP_ + part*16, v);
    store_bf16x8(sX + r*KP_ + part*16 + 8, v+8);
  }
  __syncthreads();
  // phase 3: GEMM_MAa -> sH1 (W_MAb loads in flight)
  stageLoad(WtMAb);
  {
    f32x4 acc[2][2];
    acc[0][0]=(f32x4)0.f; acc[0][1]=(f32x4)0.f;
    acc[1][0]=(f32x4)0.f; acc[1][1]=(f32x4)0.f;
    domfma(sX, acc);
    #pragma unroll
    for (int mt=0; mt<2; mt++)
      #pragma unroll
      for (int nt=0; nt<2; nt++){
        int col = n0 + nt*16 + lane15;
        float bsv = sbias[col];
        #pragma unroll
        for (int r4=0; r4<4; r4++){
          int row = mt*16 + quad*4 + r4;
          sH1[row*KP_ + col] = f2bf(gelu_erf(acc[mt][nt][r4] + bsv));
        }
      }
  }
  __syncthreads();
  stageWrite();
  if (tid < 128) sbias[tid] = bma[128 + tid];
  __syncthreads();
  // phase 4: GEMM_MAb -> sH2 (W_MBa in flight)
  stageLoad(WtMBa);
  {
    f32x4 acc[2][2];
    acc[0][0]=(f32x4)0.f; acc[0][1]=(f32x4)0.f;
    acc[1][0]=(f32x4)0.f; acc[1][1]=(f32x4)0.f;
    domfma(sX, acc);
    #pragma unroll
    for (int mt=0; mt<2; mt++)
      #pragma unroll
      for (int nt=0; nt<2; nt++){
        int col = n0 + nt*16 + lane15;
        float bsv = sbias[col];
        #pragma unroll
        for (int r4=0; r4<4; r4++){
          int row = mt*16 + quad*4 + r4;
          sH2[row*KP_ + col] = f2bf(gelu_erf(acc[mt][nt][r4] + bsv));
        }
      }
  }
  __syncthreads();
  stageWrite();
  if (tid < 128) sbias[tid] = bmb[tid];
  __syncthreads();
  // phase 5: GEMM_MBa(sH1) -> acc (W_MBb in flight)
  stageLoad(WtMBb);
  f32x4 acc[2][2];
  acc[0][0]=(f32x4)0.f; acc[0][1]=(f32x4)0.f;
  acc[1][0]=(f32x4)0.f; acc[1][1]=(f32x4)0.f;
  domfma(sH1, acc);
  __syncthreads();
  stageWrite();
  __syncthreads();
  // phase 6: GEMM_MBb(sH2) -> acc (+W_Q2 in flight for stage 1)
  if (WtQ2) stageLoad(WtQ2);
  domfma(sH2, acc);
  if (out == nullptr){
    // stage 1: Q1 fp32 + fused stage-2 q projection into QPout
    #pragma unroll
    for (int mt=0; mt<2; mt++)
      #pragma unroll
      for (int nt=0; nt<2; nt++){
        int col = n0 + nt*16 + lane15;
        float bsv = sbias[col];
        #pragma unroll
        for (int r4=0; r4<4; r4++){
          int row = mt*16 + quad*4 + r4;
          float v = acc[mt][nt][r4] + bsv + sCUR[row*132 + col];
          sCUR[row*132 + col] = v;
          Q1out[(size_t)(base+row)*128 + col] = v;
        }
      }
    __syncthreads();
    {
      const int r = tid >> 3, part = tid & 7;
      float s=0.f, s2=0.f;
      #pragma unroll
      for (int k=0;k<16;k++){
        float v = sCUR[r*132 + part*16 + k];
        s += v; s2 = fmaf(v,v,s2);
      }
      #pragma unroll
      for (int off=4; off>0; off>>=1){ s += __shfl_xor(s, off, 8); s2 += __shfl_xor(s2, off, 8); }
      if (part == 0){
        float mean = s*(1.f/128.f);
        sMean[r] = mean;
        sRstd[r] = rsqrtf(fmaxf(s2*(1.f/128.f) - mean*mean, 0.f) + 1e-5f);
      }
    }
    __syncthreads();
    {
      const int r = tid >> 3, part = tid & 7;
      float mean = sMean[r], rstd = sRstd[r];
      float v[16];
      #pragma unroll
      for (int k=0;k<16;k++) v[k] = (sCUR[r*132 + part*16 + k] - mean)*rstd;
      store_bf16x8(sX + r*KP_ + part*16, v);
      store_bf16x8(sX + r*KP_ + part*16 + 8, v+8);
    }
    stageWrite();                         // W_Q2 -> sW
    if (tid < 128) sbias[tid] = q2bias[tid];
    __syncthreads();
    f32x4 a2[2][2];
    a2[0][0]=(f32x4)0.f; a2[0][1]=(f32x4)0.f;
    a2[1][0]=(f32x4)0.f; a2[1][1]=(f32x4)0.f;
    domfma(sX, a2);
    #pragma unroll
    for (int mt=0; mt<2; mt++)
      #pragma unroll
      for (int nt=0; nt<2; nt++){
        int col = n0 + nt*16 + lane15;
        float bsv = sbias[col];
        #pragma unroll
        for (int r4=0; r4<4; r4++){
          int row = mt*16 + quad*4 + r4;
          sH1[row*KP_ + col] = f2bf((a2[mt][nt][r4] + bsv) * q2scale);
        }
      }
    __syncthreads();
    for (int i = tid; i < 512; i += 256){
      int row = i >> 4, seg = i & 15;
      *(short8*)(QPout + (size_t)(base+row)*128 + seg*8) = *(const short8*)&sH1[row*KP_ + seg*8];
    }
  } else {
    float res[2][2][4];
    #pragma unroll
    for (int mt=0; mt<2; mt++)
      #pragma unroll
      for (int nt=0; nt<2; nt++){
        int col = n0 + nt*16 + lane15;
        float bsv = sbias[col];
        #pragma unroll
        for (int r4=0; r4<4; r4++){
          int row = mt*16 + quad*4 + r4;
          res[mt][nt][r4] = acc[mt][nt][r4] + bsv + sCUR[row*132 + col];
        }
      }
    __syncthreads();
    #pragma unroll
    for (int mt=0; mt<2; mt++)
      #pragma unroll
      for (int nt=0; nt<2; nt++){
        int col = n0 + nt*16 + lane15;
        #pragma unroll
        for (int r4=0; r4<4; r4++){
          int row = mt*16 + quad*4 + r4;
          sCUR[row*132 + col] = res[mt][nt][r4];
        }
      }
    __syncthreads();
    {
      const int r = tid >> 3, part = tid & 7;
      float s=0.f, s2=0.f;
      #pragma unroll
      for (int k=0;k<16;k++){
        float v = sCUR[r*132 + part*16 + k];
        s += v; s2 = fmaf(v,v,s2);
      }
      #pragma unroll
      for (int off=4; off>0; off>>=1){ s += __shfl_xor(s, off, 8); s2 += __shfl_xor(s2, off, 8); }
      if (part == 0){
        float mean = s*(1.f/128.f);
        sMean[r] = mean;
        sRstd[r] = rsqrtf(fmaxf(s2*(1.f/128.f) - mean*mean, 0.f) + 1e-5f);
      }
    }
    __syncthreads();
    {
      int c = tid & 127, half = tid >> 7;
      int b = base >> 12, l = (base >> 6) & 63, p0 = base & 63;
      float go = postg[c], bo = postb[c];
      #pragma unroll
      for (int seg=0; seg<2; seg++){
        int p = p0 + half*16 + seg*8;
        int hrow = (l>>3)*8 + (p>>3);
        int w0 = (l&7)*8;
        float rr[8];
        #pragma unroll
        for (int j=0;j<8;j++){
          int row = half*16 + seg*8 + j;
          rr[j] = fmaf((sCUR[row*132 + c] - sMean[row])*sRstd[row], go, bo);
        }
        size_t obase = ((size_t)(b*128 + c))*4096 + (size_t)hrow*64 + w0;
        *(float4*)&out[obase]   = make_float4(rr[0],rr[1],rr[2],rr[3]);
        *(float4*)&out[obase+4] = make_float4(rr[4],rr[5],rr[6],rr[7]);
      }
    }
  }
}

// ---------------- MFMA attention (pair-packed V staging, Q prefetch) --------
__global__ __launch_bounds__(256) void k_attn2(const unsigned short* __restrict__ QPh,
    const unsigned short* __restrict__ KPh, const unsigned short* __restrict__ VPh,
    unsigned short* __restrict__ AOh, int nrep, int nQ){
  __shared__ unsigned short Ksh[288*40];
  __shared__ unsigned short Vt[32*296];
  __shared__ unsigned short Psh[4*16*40];
  __shared__ float rs[4*16];
  int hd = blockIdx.x & 3; int bl = blockIdx.x >> 2;
  size_t kvbase = (size_t)bl*264;
  int tid = threadIdx.x;
  const int wv = tid >> 6, lane = tid & 63;
  const int lane15 = lane & 15, quad = lane >> 4;
  // T14: cam-0 Q fragment load issued before staging (hides under it)
  short8 qf_cur = *(const short8*)(QPh +
      (size_t)(bl*nQ + wv*16 + lane15)*128 + hd*32 + quad*8);
  for (int idx = tid; idx < 1056; idx += 256){
    int row = idx >> 2, seg = idx & 3;
    *(short8*)&Ksh[row*40 + seg*8] =
      *(const short8*)(KPh + (kvbase+row)*128 + hd*32 + seg*8);
  }
  for (int idx = tid; idx < 96; idx += 256){
    int row = 264 + (idx>>2), seg = idx & 3;
    short8 z = {0,0,0,0,0,0,0,0};
    *(short8*)&Ksh[row*40 + seg*8] = z;
  }
  for (int idx = tid; idx < 528; idx += 256){   // V transpose: 132 key-pairs x 4 segs
    int kp = idx >> 2, seg = idx & 3;
    union { short8 s; unsigned short u[8]; } a, b;
    a.s = *(const short8*)(VPh + (kvbase + 2*kp)*128 + hd*32 + seg*8);
    b.s = *(const short8*)(VPh + (kvbase + 2*kp + 1)*128 + hd*32 + seg*8);
    #pragma unroll
    for (int i=0;i<8;i++)
      *(unsigned*)&Vt[(seg*8+i)*296 + 2*kp] = (unsigned)a.u[i] | ((unsigned)b.u[i] << 16);
  }
  for (int idx = tid; idx < 384; idx += 256){
    int d = idx / 12, kp = 264 + (idx % 12)*2;
    *(unsigned*)&Vt[d*296 + kp] = 0u;
  }
  __syncthreads();
  unsigned short* Pw = Psh + wv*640;
  float* rsw = rs + wv*16;
  short8 vfrag[9][2];
  #pragma unroll
  for (int kc=0; kc<9; kc++){
    vfrag[kc][0] = *(const short8*)&Vt[(lane15)*296      + kc*32 + quad*8];
    vfrag[kc][1] = *(const short8*)&Vt[(16+lane15)*296   + kc*32 + quad*8];
  }
  f32x4 macc0 = (f32x4)0.f, macc1 = (f32x4)0.f;
  for (int cam = 0; cam < nrep; cam++){
    short8 qf = qf_cur;
    if (cam + 1 < nrep){                      // prefetch next cam's fragment
      int qrown = bl*nQ + ((cam+1)*4 + wv)*16 + lane15;
      qf_cur = *(const short8*)(QPh + (size_t)qrown*128 + hd*32 + quad*8);
    }
    f32x4 oa0 = (f32x4)0.f, oa1 = (f32x4)0.f;
    float rsum = 0.f;
    #pragma unroll
    for (int kc=0; kc<9; kc++){
      #pragma unroll
      for (int sub=0; sub<2; sub++){
        int kt = kc*2 + sub;
        short8 kf = *(const short8*)&Ksh[(kt*16 + lane15)*40 + quad*8];
        f32x4 st = __builtin_amdgcn_mfma_f32_16x16x32_bf16(kf, qf, (f32x4)0.f, 0,0,0);
        int kbase = kt*16 + quad*4;
        float e0 = (kbase+0 < 264) ? __expf(st[0]) : 0.f;
        float e1 = (kbase+1 < 264) ? __expf(st[1]) : 0.f;
        float e2 = (kbase+2 < 264) ? __expf(st[2]) : 0.f;
        float e3 = (kbase+3 < 264) ? __expf(st[3]) : 0.f;
        rsum += (e0+e1)+(e2+e3);
        uint2 pk;
        pk.x = (unsigned)f2bf(e0) | ((unsigned)f2bf(e1) << 16);
        pk.y = (unsigned)f2bf(e2) | ((unsigned)f2bf(e3) << 16);
        *(uint2*)&Pw[lane15*40 + sub*16 + quad*4] = pk;
      }
      short8 pf = *(const short8*)&Pw[lane15*40 + quad*8];
      oa0 = __builtin_amdgcn_mfma_f32_16x16x32_bf16(pf, vfrag[kc][0], oa0, 0,0,0);
      oa1 = __builtin_amdgcn_mfma_f32_16x16x32_bf16(pf, vfrag[kc][1], oa1, 0,0,0);
    }
    rsum += __shfl_xor(rsum, 16);
    rsum += __shfl_xor(rsum, 32);
    if (lane < 16) rsw[lane] = rsum;
    f32x4 rv = *(f32x4*)&rsw[quad*4];
    #pragma unroll
    for (int r=0;r<4;r++){
      float inv = 1.f / rv[r];
      macc0[r] = fmaf(oa0[r], inv, macc0[r]);
      macc1[r] = fmaf(oa1[r], inv, macc1[r]);
    }
  }
  float sc = (nrep == 6) ? (1.f/6.f) : 1.f;
  int pixb = wv*16 + quad*4;
  #pragma unroll
  for (int r=0;r<4;r++){
    size_t rowo = ((size_t)(bl*64 + pixb + r))*128 + hd*32;
    AOh[rowo + lane15]      = f2bf(macc0[r]*sc);
    AOh[rowo + 16 + lane15] = f2bf(macc1[r]*sc);
  }
}

extern "C" void kernel_launch(void* const* d_in, const int* in_sizes, int n_in,
                              void* d_out, int out_size, void* d_ws, size_t ws_size,
                              hipStream_t stream) {
  (void)in_sizes; (void)n_in; (void)out_size; (void)ws_size;
  const float* x     = (const float*)d_in[1];
  const float* gridp = (const float*)d_in[2];
  const float* feat  = (const float*)d_in[3];
  const float* Iinv  = (const float*)d_in[4];
  const float* Einv  = (const float*)d_in[5];
  const float* gfl   = (const float*)d_in[6];
  const float* bfl   = (const float*)d_in[7];
  const float* Wfl   = (const float*)d_in[8];
  const float* gfp   = (const float*)d_in[9];
  const float* bfp   = (const float*)d_in[10];
  const float* Wfp   = (const float*)d_in[11];
  const float* Wbev  = (const float*)d_in[12];
  const float* bbev  = (const float*)d_in[13];
  const float* Wimg  = (const float*)d_in[14];
  const float* Wcam  = (const float*)d_in[15];
  const float* alng  = (const float*)d_in[16];
  const float* alnb  = (const float*)d_in[17];
  const float* aWqkv = (const float*)d_in[18];
  const float* abqkv = (const float*)d_in[19];
  const float* aWp   = (const float*)d_in[20];
  const float* abp   = (const float*)d_in[21];
  const float* png   = (const float*)d_in[22];
  const float* pnb   = (const float*)d_in[23];
  const float* Wma   = (const float*)d_in[24];
  const float* bma   = (const float*)d_in[25];
  const float* Wmb   = (const float*)d_in[26];
  const float* bmb   = (const float*)d_in[27];
  const float* postg = (const float*)d_in[28];
  const float* postb = (const float*)d_in[29];
  float* out = (float*)d_out;
  float* ws  = (float*)d_ws;
  const float QSC = 0.17677669529663687f;

  float* biasP = ws;                                   // 768 fp32 (reserve 2048)
  unsigned short* Wt   = (unsigned short*)(ws + 2048);
  unsigned short* K1h  = (unsigned short*)(ws + 149504);   // (free slot)
  unsigned short* V1h  = K1h + 4325376;                    // (free slot)
  unsigned short* KPh  = V1h + 4325376;
  unsigned short* VPh  = KPh + 4325376;
  unsigned short* KP2h = VPh + 4325376;
  unsigned short* VP2h = KP2h + 4325376;
  unsigned short* QPh  = VP2h + 4325376;               // 49152x128
  unsigned short* Qbh  = QPh + 6291456;                // (unused, layout kept)
  unsigned short* AOh  = Qbh + 6291456;
  float* Q1f = (float*)(AOh + 1048576);                // 8192x128 fp32

  unsigned short* WtQ2 = Wt + 49152;
  unsigned short* WtP1 = Wt + 98304;    unsigned short* WtP2 = Wt + 114688;
  unsigned short* WtMA1 = Wt + 131072;  unsigned short* WtMA2 = Wt + 163840;
  unsigned short* WtMB1a = Wt + 196608; unsigned short* WtMB1b = Wt + 212992;
  unsigned short* WtMB2a = Wt + 229376; unsigned short* WtMB2b = Wt + 245760;

  // 1) fused prep+conv+KV-proj (conv 528 | bevq 512 | wprep 36 | bias 1)
  k_prepconv<<<1077, 256, 0, stream>>>(aWqkv, aWp, Wma, Wmb, Wt,
      abqkv, biasP, gridp, Wbev, bbev, x, alng, alnb, Einv, Wcam, QPh,
      feat, gfp, bfp, Wfp, gfl, bfl, Wfl, Iinv, Wimg,
      KPh, KP2h, VPh, VP2h);

  // 2) stage-1 attention
  k_attn2<<<512, 256, 0, stream>>>(QPh, KPh, VPh, AOh, 6, 384);
  // 3) stage-1 tail: P+x-skip+LN+MA+gelu+MB -> Q1f, then fused q2-proj -> QPh
  k_tail<<<256, 256, 0, stream>>>(AOh, x, 1, WtP1, abp, png, pnb,
      WtMA1, WtMA1+16384, bma, WtMB1a, WtMB1b, bmb, Q1f,
      WtQ2, biasP+384, QSC, QPh,
      nullptr, nullptr, nullptr);
  // 4) stage-2 attention
  k_attn2<<<512, 256, 0, stream>>>(QPh, KP2h, VP2h, AOh, 1, 64);
  // 5) stage-2 tail (+final LN) -> out
  k_tail<<<256, 256, 0, stream>>>(AOh, Q1f, 3, WtP2, abp+128, png+128, pnb+128,
      WtMA2, WtMA2+16384, bma+256, WtMB2a, WtMB2b, bmb+128, nullptr,
      nullptr, nullptr, 0.f, nullptr,
      postg, postb, out);
}

// Round 9
// 242.821 us; speedup vs baseline: 1.0754x; 1.0754x over previous
//
#include <hip/hip_runtime.h>
#include <math.h>

// CrossViewSwapAttention forward. Round 20: R18 conv revert + attn Q-prefetch.
// R19's conv weight reg-prefetch reverted (VGPR 124->172 killed occupancy;
// rule: T14 only when staging regs fit under the VGPR ceiling). k_prepconv
// = exact R18. k_attn2 keeps the 1-deep Q-fragment prefetch (4 VGPR).
// k_tail = R18 (T14 staged weights). 5 dispatches.
// B=2 N=6 H=W=64 FH=32 FW=88 DIM=128 HEADS=4 DH=32 QW=8x8 KW=4x11

typedef __attribute__((ext_vector_type(8))) short short8;
typedef __attribute__((ext_vector_type(4))) float f32x4;

__device__ __forceinline__ unsigned short f2bf(float f){
  union { float f; unsigned u; } v; v.f = f;
  unsigned r = v.u + 0x7FFF + ((v.u >> 16) & 1);   // RNE
  return (unsigned short)(r >> 16);
}
__device__ __forceinline__ float bf2f(unsigned short h){
  union { unsigned u; float f; } v; v.u = ((unsigned)h) << 16; return v.f;
}
__device__ __forceinline__ void store_bf16x8(unsigned short* p, const float* v){
  union { short8 s8; unsigned short u[8]; } u;
  #pragma unroll
  for (int i=0;i<8;i++) u.u[i] = f2bf(v[i]);
  *(short8*)p = u.s8;
}

__device__ __forceinline__ float gelu_erf(float x){
  float z = x * 0.70710678118654752f;
  float a = fabsf(z);
  float t = 1.0f / fmaf(0.3275911f, a, 1.0f);
  float p = t*(0.254829592f + t*(-0.284496736f + t*(1.421413741f +
            t*(-1.453152027f + t*1.061405429f))));
  float er = 1.0f - p*__expf(-a*a);
  er = copysignf(er, z);
  return 0.5f * x * (1.0f + er);
}

__device__ __forceinline__ size_t remap_kv(int tok, int mode){
  int bn = tok / 2816; int p = tok - bn*2816;
  int b = bn / 6, n = bn - b*6;
  int i = p / 88, j = p - i*88;
  int l, t;
  if (mode == 1){
    int jw = j / 11;
    l = (i >> 2)*8 + jw;
    t = n*44 + (i & 3)*11 + (j - jw*11);
  } else {
    l = (i & 7)*8 + (j & 7);
    t = n*44 + (i >> 3)*11 + (j >> 3);
  }
  return (size_t)((b*64 + l)*264 + t);
}

// == fused dispatch 1: conv(+geom+LN+dual KV proj) | bevq(+Q1) | wprep | bias
// grid: [0,528) conv, [528,1040) bevq, [1040,1076) wprep, [1076,1077) bias3
__global__ __launch_bounds__(256) void k_prepconv(
    const float* __restrict__ qkv, const float* __restrict__ wp,
    const float* __restrict__ wma, const float* __restrict__ wmb,
    unsigned short* __restrict__ Wt,
    const float* __restrict__ abqkv, float* __restrict__ biasP,
    const float* __restrict__ gridp, const float* __restrict__ Wbev,
    const float* __restrict__ bbev, const float* __restrict__ x,
    const float* __restrict__ lg, const float* __restrict__ lb,
    const float* __restrict__ Einv, const float* __restrict__ Wcam,
    unsigned short* __restrict__ QPh,
    const float* __restrict__ feat,
    const float* __restrict__ gfp, const float* __restrict__ bfp,
    const float* __restrict__ Wfp,
    const float* __restrict__ gfl, const float* __restrict__ bfl,
    const float* __restrict__ Wfl,
    const float* __restrict__ Iinv, const float* __restrict__ Wimg,
    unsigned short* __restrict__ KPh, unsigned short* __restrict__ KP2h,
    unsigned short* __restrict__ VPh, unsigned short* __restrict__ VP2h){
  constexpr int KP_ = 136;
  __shared__ unsigned short sW[128*KP_];
  __shared__ unsigned short sA[128*KP_];
  __shared__ __align__(16) float sMisc[2560];
  const int bid = blockIdx.x;
  const int tid = threadIdx.x;

  if (bid < 528){
    float* sg_  = sMisc;
    float* sb_  = sMisc + 128;
    float* sMean= sMisc + 256;
    float* sRstd= sMisc + 384;
    float* sRn  = sMisc + 512;
    float* sCE  = sMisc + 640;
    float4* sWI4= (float4*)(sMisc + 768);
    float* sIE  = sMisc + 1280;
    float* sB1  = sMisc + 1312;
    float* sB2  = sMisc + 1440;
    const int which = (bid >= 264);
    const int cbid = which ? bid - 264 : bid;
    const int m1 = which ? 2 : 1;
    const int m2 = which ? 5 : 4;
    const float* gg = which ? gfl : gfp;
    const float* bb = which ? bfl : bfp;
    const float* Wf = which ? Wfl : Wfp;
    unsigned short* Oa = which ? VPh : KPh;
    unsigned short* Ob = which ? VP2h : KP2h;
    const int base = cbid * 128;
    const int bn = base / 2816;
    const int pbase = base - bn*2816;
    if (tid < 128){ sg_[tid]=gg[tid]; sb_[tid]=bb[tid]; }
    if (!which){
      if (tid < 128){
        const float* E = Einv + bn*16;
        float4 wc = *(const float4*)(Wcam + tid*4);
        sCE[tid] = wc.x*E[3] + wc.y*E[7] + wc.z*E[11] + wc.w*E[15];
        sWI4[tid] = *(const float4*)(Wimg + tid*4);
      }
      if (tid < 25) sIE[tid] = (tid < 9) ? Iinv[bn*9 + tid] : Einv[bn*16 + (tid-9)];
    }
    for (int i = tid; i < 2048; i += 256){
      int n = i >> 4, k8 = (i & 15) << 3;
      const float* wsp = Wf + (size_t)n*128 + k8;
      float4 f0 = *(const float4*)wsp;
      float4 f1 = *(const float4*)(wsp+4);
      float v8[8] = {f0.x,f0.y,f0.z,f0.w,f1.x,f1.y,f1.z,f1.w};
      store_bf16x8(&sW[n*KP_ + k8], v8);
    }
    {
      int n = tid & 127, wsel = tid >> 7;
      int m = wsel ? m2 : m1;
      const float* W = qkv + m*16384;
      const float* lnb = lb + m*128;
      float s = abqkv[m*128 + n];
      for (int k=0;k<128;k++) s = fmaf(lnb[k], W[k*128 + n], s);
      (wsel ? sB2 : sB1)[n] = s;
    }
    const float RSQ = rsqrtf(1.0f + 1e-5f);
    {
      int prow = tid & 127, cseg = tid >> 7;
      int p = pbase + prow;
      const float* fb = feat + ((size_t)bn*128 + cseg*64)*2816 + p;
      #pragma unroll 8
      for (int i=0;i<64;i+=2){
        int c = cseg*64 + i;
        float t0 = fb[(size_t)i*2816] * RSQ;
        float t1 = fb[(size_t)(i+1)*2816] * RSQ;
        float y0 = fmaxf(fmaf(t0, sg_[c],   sb_[c]),   0.f);
        float y1 = fmaxf(fmaf(t1, sg_[c+1], sb_[c+1]), 0.f);
        unsigned u = (unsigned)f2bf(y0) | ((unsigned)f2bf(y1) << 16);
        *(unsigned*)&sA[prow*KP_ + c] = u;
      }
    }
    __syncthreads();
    const int lane = tid & 63, wv = tid >> 6;
    const int lane15 = lane & 15, quad = lane >> 4;
    const int n0 = wv * 32;
    const unsigned short* aptr = sA + lane15*KP_ + quad*8;
    const unsigned short* bptr = sW + (size_t)(n0 + lane15)*KP_ + quad*8;
    f32x4 acc[8][2];
    #pragma unroll
    for (int mt=0; mt<8; mt++){ acc[mt][0]=(f32x4)0.f; acc[mt][1]=(f32x4)0.f; }
    #pragma unroll
    for (int kk=0; kk<4; kk++){
      short8 af[8], bf2v[2];
      #pragma unroll
      for (int mt=0; mt<8; mt++) af[mt] = *(const short8*)(aptr + mt*16*KP_ + kk*32);
      bf2v[0] = *(const short8*)(bptr + kk*32);
      bf2v[1] = *(const short8*)(bptr + 16*KP_ + kk*32);
      #pragma unroll
      for (int mt=0; mt<8; mt++){
        acc[mt][0] = __builtin_amdgcn_mfma_f32_16x16x32_bf16(af[mt], bf2v[0], acc[mt][0], 0,0,0);
        acc[mt][1] = __builtin_amdgcn_mfma_f32_16x16x32_bf16(af[mt], bf2v[1], acc[mt][1], 0,0,0);
      }
    }
    __syncthreads();
    if (!which){
      const int r = tid >> 1, half = tid & 1;
      int p = pbase + r;
      int ii = p / 88, jj = p - ii*88;
      float xs = (float)jj * (480.0f/87.0f);
      float ys = (float)ii * (224.0f/31.0f);
      float c0 = sIE[0]*xs + sIE[1]*ys + sIE[2];
      float c1 = sIE[3]*xs + sIE[4]*ys + sIE[5];
      float c2 = sIE[6]*xs + sIE[7]*ys + sIE[8];
      float d0 = sIE[9]*c0  + sIE[10]*c1 + sIE[11]*c2 + sIE[12];
      float d1 = sIE[13]*c0 + sIE[14]*c1 + sIE[15]*c2 + sIE[16];
      float d2 = sIE[17]*c0 + sIE[18]*c1 + sIE[19]*c2 + sIE[20];
      float d3 = sIE[21]*c0 + sIE[22]*c1 + sIE[23]*c2 + sIE[24];
      float sq = 0.f;
      #pragma unroll 8
      for (int k=0;k<64;k++){
        int c = half*64 + k;
        float4 w = sWI4[c];
        float de = w.x*d0 + w.y*d1 + w.z*d2 + w.w*d3 - sCE[c];
        sA[r*KP_ + c] = f2bf(de);
        sq = fmaf(de, de, sq);
      }
      sq += __shfl_xor(sq, 1);
      if (half == 0) sRn[r] = 1.0f / fmaxf(sqrtf(sq), 1e-12f);
    }
    {
      const float* Wsrc = qkv + m1*16384;
      const float* gvv = lg + m1*128;
      for (int idx = tid; idx < 8192; idx += 256){
        int n = idx & 127, k2 = (idx >> 7) << 1;
        float v0 = Wsrc[(size_t)k2*128 + n]     * gvv[k2];
        float v1 = Wsrc[(size_t)(k2+1)*128 + n] * gvv[k2+1];
        *(unsigned*)&sW[n*KP_ + k2] = (unsigned)f2bf(v0) | ((unsigned)f2bf(v1) << 16);
      }
    }
    __syncthreads();
    #pragma unroll
    for (int mt=0; mt<8; mt++){
      #pragma unroll
      for (int nt=0; nt<2; nt++){
        int col = n0 + nt*16 + lane15;
        #pragma unroll
        for (int r4=0; r4<4; r4++){
          int row = mt*16 + quad*4 + r4;
          float v = acc[mt][nt][r4];
          if (!which) v += bf2f(sA[row*KP_ + col]) * sRn[row];   // + geom
          sA[row*KP_ + col] = f2bf(v);
        }
      }
    }
    __syncthreads();
    {
      int r = tid >> 1, part = tid & 1;
      float s=0.f, s2=0.f;
      #pragma unroll 8
      for (int k=0;k<64;k++){
        float v = bf2f(sA[r*KP_ + part*64 + k]);
        s += v; s2 = fmaf(v,v,s2);
      }
      s += __shfl_xor(s, 1); s2 += __shfl_xor(s2, 1);
      if (part == 0){
        float mean = s*(1.f/128.f);
        sMean[r] = mean;
        sRstd[r] = rsqrtf(fmaxf(s2*(1.f/128.f) - mean*mean, 0.f) + 1e-5f);
      }
    }
    __syncthreads();
    for (int i = tid; i < 2048; i += 256){
      int row = i >> 4, seg = i & 15;
      float mean = sMean[row], rstd = sRstd[row];
      union { short8 s; unsigned short u[8]; } t;
      t.s = *(const short8*)&sA[row*KP_ + seg*8];
      float v[8];
      #pragma unroll
      for (int k=0;k<8;k++) v[k] = (bf2f(t.u[k]) - mean)*rstd;
      store_bf16x8(&sA[row*KP_ + seg*8], v);
    }
    __syncthreads();
    #pragma unroll
    for (int mt=0; mt<8; mt++){ acc[mt][0]=(f32x4)0.f; acc[mt][1]=(f32x4)0.f; }
    #pragma unroll
    for (int kk=0; kk<4; kk++){
      short8 af[8], bf2v[2];
      #pragma unroll
      for (int mt=0; mt<8; mt++) af[mt] = *(const short8*)(aptr + mt*16*KP_ + kk*32);
      bf2v[0] = *(const short8*)(bptr + kk*32);
      bf2v[1] = *(const short8*)(bptr + 16*KP_ + kk*32);
      #pragma unroll
      for (int mt=0; mt<8; mt++){
        acc[mt][0] = __builtin_amdgcn_mfma_f32_16x16x32_bf16(af[mt], bf2v[0], acc[mt][0], 0,0,0);
        acc[mt][1] = __builtin_amdgcn_mfma_f32_16x16x32_bf16(af[mt], bf2v[1], acc[mt][1], 0,0,0);
      }
    }
    __syncthreads();
    #pragma unroll
    for (int mt=0; mt<8; mt++){
      #pragma unroll
      for (int nt=0; nt<2; nt++){
        int col = n0 + nt*16 + lane15;
        float bsv = sB1[col];
        #pragma unroll
        for (int r4=0; r4<4; r4++){
          int row = mt*16 + quad*4 + r4;
          sW[row*KP_ + col] = f2bf(acc[mt][nt][r4] + bsv);
        }
      }
    }
    __syncthreads();
    for (int i = tid; i < 2048; i += 256){
      int row = i >> 4, seg = i & 15;
      size_t orow = remap_kv(base + row, 1);
      *(short8*)(Oa + orow*128 + seg*8) = *(const short8*)&sW[row*KP_ + seg*8];
    }
    __syncthreads();
    {
      const float* Wsrc = qkv + m2*16384;
      const float* gvv = lg + m2*128;
      for (int idx = tid; idx < 8192; idx += 256){
        int n = idx & 127, k2 = (idx >> 7) << 1;
        float v0 = Wsrc[(size_t)k2*128 + n]     * gvv[k2];
        float v1 = Wsrc[(size_t)(k2+1)*128 + n] * gvv[k2+1];
        *(unsigned*)&sW[n*KP_ + k2] = (unsigned)f2bf(v0) | ((unsigned)f2bf(v1) << 16);
      }
    }
    __syncthreads();
    #pragma unroll
    for (int mt=0; mt<8; mt++){ acc[mt][0]=(f32x4)0.f; acc[mt][1]=(f32x4)0.f; }
    #pragma unroll
    for (int kk=0; kk<4; kk++){
      short8 af[8], bf2v[2];
      #pragma unroll
      for (int mt=0; mt<8; mt++) af[mt] = *(const short8*)(aptr + mt*16*KP_ + kk*32);
      bf2v[0] = *(const short8*)(bptr + kk*32);
      bf2v[1] = *(const short8*)(bptr + 16*KP_ + kk*32);
      #pragma unroll
      for (int mt=0; mt<8; mt++){
        acc[mt][0] = __builtin_amdgcn_mfma_f32_16x16x32_bf16(af[mt], bf2v[0], acc[mt][0], 0,0,0);
        acc[mt][1] = __builtin_amdgcn_mfma_f32_16x16x32_bf16(af[mt], bf2v[1], acc[mt][1], 0,0,0);
      }
    }
    __syncthreads();
    #pragma unroll
    for (int mt=0; mt<8; mt++){
      #pragma unroll
      for (int nt=0; nt<2; nt++){
        int col = n0 + nt*16 + lane15;
        float bsv = sB2[col];
        #pragma unroll
        for (int r4=0; r4<4; r4++){
          int row = mt*16 + quad*4 + r4;
          sA[row*KP_ + col] = f2bf(acc[mt][nt][r4] + bsv);
        }
      }
    }
    __syncthreads();
    for (int i = tid; i < 2048; i += 256){
      int row = i >> 4, seg = i & 15;
      size_t orow = remap_kv(base + row, 2);
      *(short8*)(Ob + orow*128 + seg*8) = *(const short8*)&sA[row*KP_ + seg*8];
    }
  } else if (bid < 1040){
    // ---- bevq + fused Q1 projection -> QPh (16 pixels/block) ----
    const float QSCALE = 0.17677669529663687f;
    float* sx = sMisc;
    int* rowoff = (int*)(sMisc + 2176);
    int bid2 = bid - 528;
    int b = bid2 >> 8; int pp0 = (bid2 & 255) << 4;
    // self-stage Q1 weight, 2 bf16 per dword write
    for (int idx = tid; idx < 8192; idx += 256){
      int n = idx & 127, k2 = (idx >> 7) << 1;
      float v0 = qkv[(size_t)k2*128 + n];
      float v1 = qkv[(size_t)(k2+1)*128 + n];
      *(unsigned*)&sW[n*KP_ + k2] = (unsigned)f2bf(v0) | ((unsigned)f2bf(v1) << 16);
    }
    {
      int cg = tid >> 4, px = tid & 15;
      #pragma unroll
      for (int i=0;i<8;i++){
        int c = cg + 16*i;
        sx[c*17 + px] = x[(size_t)b*524288 + (size_t)c*4096 + pp0 + px];
      }
    }
    if (tid < 16){
      int pix = pp0 + tid; int h = pix >> 6, w = pix & 63;
      int l = (h>>3)*8 + (w>>3); int tq = (h&7)*8 + (w&7);
      rowoff[tid] = (b*64 + l)*384 + tq;
    }
    __syncthreads();
    int xid = tid >> 4, part = tid & 15;
    int pix = pp0 + xid;
    float g0 = gridp[pix], g1 = gridp[4096 + pix];
    float we[8], xv[8];
    #pragma unroll
    for (int k=0;k<8;k++){
      int o = part*8 + k;
      we[k] = Wbev[o*2]*g0 + Wbev[o*2+1]*g1 + bbev[o];
      xv[k] = sx[(part*8+k)*17 + xid];
    }
    for (int n=0; n<6; n++){
      const float* E = Einv + (b*6+n)*16;
      float v[8]; float sq = 0.f;
      #pragma unroll
      for (int k=0;k<8;k++){
        int o = part*8 + k;
        const float* Wc = Wcam + o*4;
        float ce = Wc[0]*E[3] + Wc[1]*E[7] + Wc[2]*E[11] + Wc[3]*E[15];
        float vv = we[k] - ce;
        v[k] = vv; sq = fmaf(vv, vv, sq);
      }
      #pragma unroll
      for (int off=8; off>0; off>>=1) sq += __shfl_xor(sq, off, 16);
      float rn = 1.0f / fmaxf(sqrtf(sq), 1e-12f);
      float q[8]; float s=0.f, s2=0.f;
      #pragma unroll
      for (int k=0;k<8;k++){
        q[k] = fmaf(v[k], rn, xv[k]);
        s += q[k]; s2 = fmaf(q[k], q[k], s2);
      }
      #pragma unroll
      for (int off=8; off>0; off>>=1){ s += __shfl_xor(s, off, 16); s2 += __shfl_xor(s2, off, 16); }
      float mean = s*(1.f/128.f);
      float rstd = rsqrtf(fmaxf(s2*(1.f/128.f) - mean*mean, 0.f) + 1e-5f);
      float o8[8];
      #pragma unroll
      for (int k=0;k<8;k++){
        int c = part*8 + k;
        o8[k] = fmaf((q[k]-mean)*rstd, lg[c], lb[c]);
      }
      store_bf16x8(sA + (size_t)(n*16 + xid)*KP_ + part*8, o8);
    }
    __syncthreads();
    const int lane = tid & 63, wv = tid >> 6;
    const int lane15 = lane & 15, quad = lane >> 4;
    const int n0 = wv * 32;
    f32x4 acc[6][2];
    #pragma unroll
    for (int mt=0; mt<6; mt++){ acc[mt][0]=(f32x4)0.f; acc[mt][1]=(f32x4)0.f; }
    const unsigned short* aptr = sA + lane15*KP_ + quad*8;
    const unsigned short* bptr = sW + (size_t)(n0 + lane15)*KP_ + quad*8;
    #pragma unroll
    for (int kk=0; kk<4; kk++){
      short8 af[6], bf2v[2];
      #pragma unroll
      for (int mt=0; mt<6; mt++) af[mt] = *(const short8*)(aptr + mt*16*KP_ + kk*32);
      bf2v[0] = *(const short8*)(bptr + kk*32);
      bf2v[1] = *(const short8*)(bptr + 16*KP_ + kk*32);
      #pragma unroll
      for (int mt=0; mt<6; mt++){
        acc[mt][0] = __builtin_amdgcn_mfma_f32_16x16x32_bf16(af[mt], bf2v[0], acc[mt][0], 0,0,0);
        acc[mt][1] = __builtin_amdgcn_mfma_f32_16x16x32_bf16(af[mt], bf2v[1], acc[mt][1], 0,0,0);
      }
    }
    __syncthreads();
    #pragma unroll
    for (int nt=0; nt<2; nt++){
      int col = n0 + nt*16 + lane15;
      float bsv = abqkv[col];
      #pragma unroll
      for (int mt=0; mt<6; mt++){
        #pragma unroll
        for (int r4=0; r4<4; r4++){
          int row = mt*16 + quad*4 + r4;
          sA[row*KP_ + col] = f2bf((acc[mt][nt][r4] + bsv) * QSCALE);
        }
      }
    }
    __syncthreads();
    for (int i = tid; i < 1536; i += 256){
      int r = i >> 4, seg = i & 15;
      size_t grow = (size_t)rowoff[r & 15] + (r >> 4)*64;
      *(short8*)(QPh + grow*128 + seg*8) = *(const short8*)&sA[r*KP_ + seg*8];
    }
  } else if (bid < 1076){
    const int sel[9]  = {0, 1,1, 2,2, 3,3,3,3};
    const int soff[9] = {49152, 0,16384, 0,32768, 0,16384,32768,49152};
    const int doff[9] = {49152, 98304,114688, 131072,163840,
                         196608,212992,229376,245760};
    const int Ns[9]   = {128, 128,128, 256,256, 128,128,128,128};
    int bidw = bid - 1040;
    int sg = bidw >> 2, q = bidw & 3;
    const float* srcs[4] = {qkv, wp, wma, wmb};
    const float* src = srcs[sel[sg]] + soff[sg];
    unsigned short* dst = Wt + doff[sg];
    int K = 128, N = Ns[sg];
    int quarter = (K*N) >> 2;
    bool fold = (sg == 0);
    const float* gv = lg + 384;
    for (int idx = q*quarter + tid; idx < (q+1)*quarter; idx += 256){
      int n = idx / K, k = idx - n*K;
      float v = src[k*N + n];
      if (fold) v *= gv[k];
      dst[idx] = f2bf(v);
    }
  } else {
    if (tid < 128){
      int n = tid;
      const float* lnb = lb + 384;
      const float* W = qkv + 49152;
      float s = abqkv[384 + n];
      for (int k=0;k<128;k++) s = fmaf(lnb[k], W[k*128 + n], s);
      biasP[384 + n] = s;
    }
  }
}

// ---------------- fused tail (T14 staged weights): P+skip+LN+MA+gelu+MB,
// then (stage1) q2-proj or (stage2) final LN + transposed store.
__global__ __launch_bounds__(256) void k_tail(
    const unsigned short* __restrict__ AOh,
    const float* __restrict__ skipf, int skipmode,
    const unsigned short* __restrict__ WtP, const float* __restrict__ abp,
    const float* __restrict__ png, const float* __restrict__ pnb,
    const unsigned short* __restrict__ WtMAa, const unsigned short* __restrict__ WtMAb,
    const float* __restrict__ bma,
    const unsigned short* __restrict__ WtMBa, const unsigned short* __restrict__ WtMBb,
    const float* __restrict__ bmb,
    float* __restrict__ Q1out,
    const unsigned short* __restrict__ WtQ2, const float* __restrict__ q2bias,
    float q2scale, unsigned short* __restrict__ QPout,
    const float* __restrict__ postg, const float* __restrict__ postb,
    float* __restrict__ out){
  constexpr int KP_ = 136;
  __shared__ unsigned short sW[128*KP_];
  __shared__ unsigned short sX[32*KP_];
  __shared__ unsigned short sH1[32*KP_];
  __shared__ unsigned short sH2[32*KP_];
  __shared__ float sCUR[32*132];
  __shared__ float sbias[128];
  __shared__ float sg[128], sb2[128];
  __shared__ float sMean[32], sRstd[32];
  const int tid = threadIdx.x;
  const int base = blockIdx.x * 32;
  const int lane = tid & 63, wv = tid >> 6;
  const int lane15 = lane & 15, quad = lane >> 4;
  const int n0 = wv * 32;

  short8 wreg[8];
  auto stageLoad = [&](const unsigned short* Wp){
    #pragma unroll
    for (int i=0;i<8;i++){
      int idx = tid + i*256;
      int n = idx >> 4, k8 = (idx & 15) << 3;
      wreg[i] = *(const short8*)(Wp + (size_t)n*128 + k8);
    }
  };
  auto stageWrite = [&](){
    #pragma unroll
    for (int i=0;i<8;i++){
      int idx = tid + i*256;
      int n = idx >> 4, k8 = (idx & 15) << 3;
      *(short8*)&sW[n*KP_ + k8] = wreg[i];
    }
  };
  auto domfma = [&](const unsigned short* Asrc, f32x4 acc[2][2]){
    const unsigned short* aptr = Asrc + lane15*KP_ + quad*8;
    const unsigned short* bptr = sW + (size_t)(n0 + lane15)*KP_ + quad*8;
    #pragma unroll
    for (int kk=0; kk<4; kk++){
      short8 a0 = *(const short8*)(aptr + kk*32);
      short8 a1 = *(const short8*)(aptr + 16*KP_ + kk*32);
      short8 b0 = *(const short8*)(bptr + kk*32);
      short8 b1 = *(const short8*)(bptr + 16*KP_ + kk*32);
      acc[0][0] = __builtin_amdgcn_mfma_f32_16x16x32_bf16(a0,b0,acc[0][0],0,0,0);
      acc[1][0] = __builtin_amdgcn_mfma_f32_16x16x32_bf16(a1,b0,acc[1][0],0,0,0);
      acc[0][1] = __builtin_amdgcn_mfma_f32_16x16x32_bf16(a0,b1,acc[0][1],0,0,0);
      acc[1][1] = __builtin_amdgcn_mfma_f32_16x16x32_bf16(a1,b1,acc[1][1],0,0,0);
    }
  };

  // phase 0: W_P staged; attn output -> sX
  stageLoad(WtP);
  {
    const int r = tid >> 3, part = tid & 7;
    const short8* src = (const short8*)(AOh + (size_t)(base+r)*128 + part*16);
    short8* dst = (short8*)(sX + r*KP_ + part*16);
    dst[0] = src[0]; dst[1] = src[1];
  }
  if (tid < 128){ sbias[tid] = abp[tid]; sg[tid] = png[tid]; sb2[tid] = pnb[tid]; }
  stageWrite();
  __syncthreads();
  // phase 1: GEMM_P (W_MAa loads in flight underneath)
  stageLoad(WtMAa);
  {
    f32x4 acc[2][2];
    acc[0][0]=(f32x4)0.f; acc[0][1]=(f32x4)0.f;
    acc[1][0]=(f32x4)0.f; acc[1][1]=(f32x4)0.f;
    domfma(sX, acc);
    #pragma unroll
    for (int mt=0; mt<2; mt++)
      #pragma unroll
      for (int nt=0; nt<2; nt++){
        int col = n0 + nt*16 + lane15;
        float bsv = sbias[col];
        #pragma unroll
        for (int r4=0; r4<4; r4++){
          int row = mt*16 + quad*4 + r4;
          int rrow = base + row;
          float v = acc[mt][nt][r4] + bsv;
          if (skipmode == 1){
            int bb = rrow >> 12, l = (rrow >> 6) & 63, pp = rrow & 63;
            int pix = (((l>>3)*8 + (pp>>3)) << 6) + (l&7)*8 + (pp&7);
            v += skipf[(size_t)bb*524288 + (size_t)col*4096 + pix];
          } else {
            v += skipf[(size_t)rrow*128 + col];
          }
          sCUR[row*132 + col] = v;
        }
      }
  }
  __syncthreads();
  // phase 2: write W_MAa; LN -> sX
  stageWrite();
  if (tid < 128) sbias[tid] = bma[tid];
  {
    const int r = tid >> 3, part = tid & 7;
    float v[16];
    #pragma unroll
    for (int k=0;k<16;k++) v[k] = sCUR[r*132 + part*16 + k];
    float s=0.f, s2=0.f;
    #pragma unroll
    for (int k=0;k<16;k++){ s += v[k]; s2 = fmaf(v[k],v[k],s2); }
    #pragma unroll
    for (int off=4; off>0; off>>=1){ s += __shfl_xor(s, off, 8); s2 += __shfl_xor(s2, off, 8); }
    float mean = s*(1.f/128.f);
    float rstd = rsqrtf(fmaxf(s2*(1.f/128.f) - mean*mean, 0.f) + 1e-5f);
    #pragma unroll
    for (int k=0;k<16;k++){
      int c = part*16 + k;
      v[k] = fmaf((v[k]-mean)*rstd, sg[c], sb2[c]);
    }
    store_bf16x8(sX + r*KP_ + part*16, v);
    store_bf16x8(sX + r*KP_ + part*16 + 8, v+8);
  }
  __syncthreads();
  // phase 3: GEMM_MAa -> sH1 (W_MAb loads in flight)
  stageLoad(WtMAb);
  {
    f32x4 acc[2][2];
    acc[0][0]=(f32x4)0.f; acc[0][1]=(f32x4)0.f;
    acc[1][0]=(f32x4)0.f; acc[1][1]=(f32x4)0.f;
    domfma(sX, acc);
    #pragma unroll
    for (int mt=0; mt<2; mt++)
      #pragma unroll
      for (int nt=0; nt<2; nt++){
        int col = n0 + nt*16 + lane15;
        float bsv = sbias[col];
        #pragma unroll
        for (int r4=0; r4<4; r4++){
          int row = mt*16 + quad*4 + r4;
          sH1[row*KP_ + col] = f2bf(gelu_erf(acc[mt][nt][r4] + bsv));
        }
      }
  }
  __syncthreads();
  stageWrite();
  if (tid < 128) sbias[tid] = bma[128 + tid];
  __syncthreads();
  // phase 4: GEMM_MAb -> sH2 (W_MBa in flight)
  stageLoad(WtMBa);
  {
    f32x4 acc[2][2];
    acc[0][0]=(f32x4)0.f; acc[0][1]=(f32x4)0.f;
    acc[1][0]=(f32x4)0.f; acc[1][1]=(f32x4)0.f;
    domfma(sX, acc);
    #pragma unroll
    for (int mt=0; mt<2; mt++)
      #pragma unroll
      for (int nt=0; nt<2; nt++){
        int col = n0 + nt*16 + lane15;
        float bsv = sbias[col];
        #pragma unroll
        for (int r4=0; r4<4; r4++){
          int row = mt*16 + quad*4 + r4;
          sH2[row*KP_ + col] = f2bf(gelu_erf(acc[mt][nt][r4] + bsv));
        }
      }
  }
  __syncthreads();
  stageWrite();
  if (tid < 128) sbias[tid] = bmb[tid];
  __syncthreads();
  // phase 5: GEMM_MBa(sH1) -> acc (W_MBb in flight)
  stageLoad(WtMBb);
  f32x4 acc[2][2];
  acc[0][0]=(f32x4)0.f; acc[0][1]=(f32x4)0.f;
  acc[1][0]=(f32x4)0.f; acc[1][1]=(f32x4)0.f;
  domfma(sH1, acc);
  __syncthreads();
  stageWrite();
  __syncthreads();
  // phase 6: GEMM_MBb(sH2) -> acc (+W_Q2 in flight for stage 1)
  if (WtQ2) stageLoad(WtQ2);
  domfma(sH2, acc);
  if (out == nullptr){
    // stage 1: Q1 fp32 + fused stage-2 q projection into QPout
    #pragma unroll
    for (int mt=0; mt<2; mt++)
      #pragma unroll
      for (int nt=0; nt<2; nt++){
        int col = n0 + nt*16 + lane15;
        float bsv = sbias[col];
        #pragma unroll
        for (int r4=0; r4<4; r4++){
          int row = mt*16 + quad*4 + r4;
          float v = acc[mt][nt][r4] + bsv + sCUR[row*132 + col];
          sCUR[row*132 + col] = v;
          Q1out[(size_t)(base+row)*128 + col] = v;
        }
      }
    __syncthreads();
    {
      const int r = tid >> 3, part = tid & 7;
      float s=0.f, s2=0.f;
      #pragma unroll
      for (int k=0;k<16;k++){
        float v = sCUR[r*132 + part*16 + k];
        s += v; s2 = fmaf(v,v,s2);
      }
      #pragma unroll
      for (int off=4; off>0; off>>=1){ s += __shfl_xor(s, off, 8); s2 += __shfl_xor(s2, off, 8); }
      if (part == 0){
        float mean = s*(1.f/128.f);
        sMean[r] = mean;
        sRstd[r] = rsqrtf(fmaxf(s2*(1.f/128.f) - mean*mean, 0.f) + 1e-5f);
      }
    }
    __syncthreads();
    {
      const int r = tid >> 3, part = tid & 7;
      float mean = sMean[r], rstd = sRstd[r];
      float v[16];
      #pragma unroll
      for (int k=0;k<16;k++) v[k] = (sCUR[r*132 + part*16 + k] - mean)*rstd;
      store_bf16x8(sX + r*KP_ + part*16, v);
      store_bf16x8(sX + r*KP_ + part*16 + 8, v+8);
    }
    stageWrite();                         // W_Q2 -> sW
    if (tid < 128) sbias[tid] = q2bias[tid];
    __syncthreads();
    f32x4 a2[2][2];
    a2[0][0]=(f32x4)0.f; a2[0][1]=(f32x4)0.f;
    a2[1][0]=(f32x4)0.f; a2[1][1]=(f32x4)0.f;
    domfma(sX, a2);
    #pragma unroll
    for (int mt=0; mt<2; mt++)
      #pragma unroll
      for (int nt=0; nt<2; nt++){
        int col = n0 + nt*16 + lane15;
        float bsv = sbias[col];
        #pragma unroll
        for (int r4=0; r4<4; r4++){
          int row = mt*16 + quad*4 + r4;
          sH1[row*KP_ + col] = f2bf((a2[mt][nt][r4] + bsv) * q2scale);
        }
      }
    __syncthreads();
    for (int i = tid; i < 512; i += 256){
      int row = i >> 4, seg = i & 15;
      *(short8*)(QPout + (size_t)(base+row)*128 + seg*8) = *(const short8*)&sH1[row*KP_ + seg*8];
    }
  } else {
    float res[2][2][4];
    #pragma unroll
    for (int mt=0; mt<2; mt++)
      #pragma unroll
      for (int nt=0; nt<2; nt++){
        int col = n0 + nt*16 + lane15;
        float bsv = sbias[col];
        #pragma unroll
        for (int r4=0; r4<4; r4++){
          int row = mt*16 + quad*4 + r4;
          res[mt][nt][r4] = acc[mt][nt][r4] + bsv + sCUR[row*132 + col];
        }
      }
    __syncthreads();
    #pragma unroll
    for (int mt=0; mt<2; mt++)
      #pragma unroll
      for (int nt=0; nt<2; nt++){
        int col = n0 + nt*16 + lane15;
        #pragma unroll
        for (int r4=0; r4<4; r4++){
          int row = mt*16 + quad*4 + r4;
          sCUR[row*132 + col] = res[mt][nt][r4];
        }
      }
    __syncthreads();
    {
      const int r = tid >> 3, part = tid & 7;
      float s=0.f, s2=0.f;
      #pragma unroll
      for (int k=0;k<16;k++){
        float v = sCUR[r*132 + part*16 + k];
        s += v; s2 = fmaf(v,v,s2);
      }
      #pragma unroll
      for (int off=4; off>0; off>>=1){ s += __shfl_xor(s, off, 8); s2 += __shfl_xor(s2, off, 8); }
      if (part == 0){
        float mean = s*(1.f/128.f);
        sMean[r] = mean;
        sRstd[r] = rsqrtf(fmaxf(s2*(1.f/128.f) - mean*mean, 0.f) + 1e-5f);
      }
    }
    __syncthreads();
    {
      int c = tid & 127, half = tid >> 7;
      int b = base >> 12, l = (base >> 6) & 63, p0 = base & 63;
      float go = postg[c], bo = postb[c];
      #pragma unroll
      for (int seg=0; seg<2; seg++){
        int p = p0 + half*16 + seg*8;
        int hrow = (l>>3)*8 + (p>>3);
        int w0 = (l&7)*8;
        float rr[8];
        #pragma unroll
        for (int j=0;j<8;j++){
          int row = half*16 + seg*8 + j;
          rr[j] = fmaf((sCUR[row*132 + c] - sMean[row])*sRstd[row], go, bo);
        }
        size_t obase = ((size_t)(b*128 + c))*4096 + (size_t)hrow*64 + w0;
        *(float4*)&out[obase]   = make_float4(rr[0],rr[1],rr[2],rr[3]);
        *(float4*)&out[obase+4] = make_float4(rr[4],rr[5],rr[6],rr[7]);
      }
    }
  }
}

// ---------------- MFMA attention (pair-packed V staging, Q prefetch) --------
__global__ __launch_bounds__(256) void k_attn2(const unsigned short* __restrict__ QPh,
    const unsigned short* __restrict__ KPh, const unsigned short* __restrict__ VPh,
    unsigned short* __restrict__ AOh, int nrep, int nQ){
  __shared__ unsigned short Ksh[288*40];
  __shared__ unsigned short Vt[32*296];
  __shared__ unsigned short Psh[4*16*40];
  __shared__ float rs[4*16];
  int hd = blockIdx.x & 3; int bl = blockIdx.x >> 2;
  size_t kvbase = (size_t)bl*264;
  int tid = threadIdx.x;
  const int wv = tid >> 6, lane = tid & 63;
  const int lane15 = lane & 15, quad = lane >> 4;
  // T14: cam-0 Q fragment load issued before staging (hides under it)
  short8 qf_cur = *(const short8*)(QPh +
      (size_t)(bl*nQ + wv*16 + lane15)*128 + hd*32 + quad*8);
  for (int idx = tid; idx < 1056; idx += 256){
    int row = idx >> 2, seg = idx & 3;
    *(short8*)&Ksh[row*40 + seg*8] =
      *(const short8*)(KPh + (kvbase+row)*128 + hd*32 + seg*8);
  }
  for (int idx = tid; idx < 96; idx += 256){
    int row = 264 + (idx>>2), seg = idx & 3;
    short8 z = {0,0,0,0,0,0,0,0};
    *(short8*)&Ksh[row*40 + seg*8] = z;
  }
  for (int idx = tid; idx < 528; idx += 256){   // V transpose: 132 key-pairs x 4 segs
    int kp = idx >> 2, seg = idx & 3;
    union { short8 s; unsigned short u[8]; } a, b;
    a.s = *(const short8*)(VPh + (kvbase + 2*kp)*128 + hd*32 + seg*8);
    b.s = *(const short8*)(VPh + (kvbase + 2*kp + 1)*128 + hd*32 + seg*8);
    #pragma unroll
    for (int i=0;i<8;i++)
      *(unsigned*)&Vt[(seg*8+i)*296 + 2*kp] = (unsigned)a.u[i] | ((unsigned)b.u[i] << 16);
  }
  for (int idx = tid; idx < 384; idx += 256){
    int d = idx / 12, kp = 264 + (idx % 12)*2;
    *(unsigned*)&Vt[d*296 + kp] = 0u;
  }
  __syncthreads();
  unsigned short* Pw = Psh + wv*640;
  float* rsw = rs + wv*16;
  short8 vfrag[9][2];
  #pragma unroll
  for (int kc=0; kc<9; kc++){
    vfrag[kc][0] = *(const short8*)&Vt[(lane15)*296      + kc*32 + quad*8];
    vfrag[kc][1] = *(const short8*)&Vt[(16+lane15)*296   + kc*32 + quad*8];
  }
  f32x4 macc0 = (f32x4)0.f, macc1 = (f32x4)0.f;
  for (int cam = 0; cam < nrep; cam++){
    short8 qf = qf_cur;
    if (cam + 1 < nrep){                      // prefetch next cam's fragment
      int qrown = bl*nQ + ((cam+1)*4 + wv)*16 + lane15;
      qf_cur = *(const short8*)(QPh + (size_t)qrown*128 + hd*32 + quad*8);
    }
    f32x4 oa0 = (f32x4)0.f, oa1 = (f32x4)0.f;
    float rsum = 0.f;
    #pragma unroll
    for (int kc=0; kc<9; kc++){
      #pragma unroll
      for (int sub=0; sub<2; sub++){
        int kt = kc*2 + sub;
        short8 kf = *(const short8*)&Ksh[(kt*16 + lane15)*40 + quad*8];
        f32x4 st = __builtin_amdgcn_mfma_f32_16x16x32_bf16(kf, qf, (f32x4)0.f, 0,0,0);
        int kbase = kt*16 + quad*4;
        float e0 = (kbase+0 < 264) ? __expf(st[0]) : 0.f;
        float e1 = (kbase+1 < 264) ? __expf(st[1]) : 0.f;
        float e2 = (kbase+2 < 264) ? __expf(st[2]) : 0.f;
        float e3 = (kbase+3 < 264) ? __expf(st[3]) : 0.f;
        rsum += (e0+e1)+(e2+e3);
        uint2 pk;
        pk.x = (unsigned)f2bf(e0) | ((unsigned)f2bf(e1) << 16);
        pk.y = (unsigned)f2bf(e2) | ((unsigned)f2bf(e3) << 16);
        *(uint2*)&Pw[lane15*40 + sub*16 + quad*4] = pk;
      }
      short8 pf = *(const short8*)&Pw[lane15*40 + quad*8];
      oa0 = __builtin_amdgcn_mfma_f32_16x16x32_bf16(pf, vfrag[kc][0], oa0, 0,0,0);
      oa1 = __builtin_amdgcn_mfma_f32_16x16x32_bf16(pf, vfrag[kc][1], oa1, 0,0,0);
    }
    rsum += __shfl_xor(rsum, 16);
    rsum += __shfl_xor(rsum, 32);
    if (lane < 16) rsw[lane] = rsum;
    f32x4 rv = *(f32x4*)&rsw[quad*4];
    #pragma unroll
    for (int r=0;r<4;r++){
      float inv = 1.f / rv[r];
      macc0[r] = fmaf(oa0[r], inv, macc0[r]);
      macc1[r] = fmaf(oa1[r], inv, macc1[r]);
    }
  }
  float sc = (nrep == 6) ? (1.f/6.f) : 1.f;
  int pixb = wv*16 + quad*4;
  #pragma unroll
  for (int r=0;r<4;r++){
    size_t rowo = ((size_t)(bl*64 + pixb + r))*128 + hd*32;
    AOh[rowo + lane15]      = f2bf(macc0[r]*sc);
    AOh[rowo + 16 + lane15] = f2bf(macc1[r]*sc);
  }
}

extern "C" void kernel_launch(void* const* d_in, const int* in_sizes, int n_in,
                              void* d_out, int out_size, void* d_ws, size_t ws_size,
                              hipStream_t stream) {
  (void)in_sizes; (void)n_in; (void)out_size; (void)ws_size;
  const float* x     = (const float*)d_in[1];
  const float* gridp = (const float*)d_in[2];
  const float* feat  = (const float*)d_in[3];
  const float* Iinv  = (const float*)d_in[4];
  const float* Einv  = (const float*)d_in[5];
  const float* gfl   = (const float*)d_in[6];
  const float* bfl   = (const float*)d_in[7];
  const float* Wfl   = (const float*)d_in[8];
  const float* gfp   = (const float*)d_in[9];
  const float* bfp   = (const float*)d_in[10];
  const float* Wfp   = (const float*)d_in[11];
  const float* Wbev  = (const float*)d_in[12];
  const float* bbev  = (const float*)d_in[13];
  const float* Wimg  = (const float*)d_in[14];
  const float* Wcam  = (const float*)d_in[15];
  const float* alng  = (const float*)d_in[16];
  const float* alnb  = (const float*)d_in[17];
  const float* aWqkv = (const float*)d_in[18];
  const float* abqkv = (const float*)d_in[19];
  const float* aWp   = (const float*)d_in[20];
  const float* abp   = (const float*)d_in[21];
  const float* png   = (const float*)d_in[22];
  const float* pnb   = (const float*)d_in[23];
  const float* Wma   = (const float*)d_in[24];
  const float* bma   = (const float*)d_in[25];
  const float* Wmb   = (const float*)d_in[26];
  const float* bmb   = (const float*)d_in[27];
  const float* postg = (const float*)d_in[28];
  const float* postb = (const float*)d_in[29];
  float* out = (float*)d_out;
  float* ws  = (float*)d_ws;
  const float QSC = 0.17677669529663687f;

  float* biasP = ws;                                   // 768 fp32 (reserve 2048)
  unsigned short* Wt   = (unsigned short*)(ws + 2048);
  unsigned short* K1h  = (unsigned short*)(ws + 149504);   // (free slot)
  unsigned short* V1h  = K1h + 4325376;                    // (free slot)
  unsigned short* KPh  = V1h + 4325376;
  unsigned short* VPh  = KPh + 4325376;
  unsigned short* KP2h = VPh + 4325376;
  unsigned short* VP2h = KP2h + 4325376;
  unsigned short* QPh  = VP2h + 4325376;               // 49152x128
  unsigned short* Qbh  = QPh + 6291456;                // (unused, layout kept)
  unsigned short* AOh  = Qbh + 6291456;
  float* Q1f = (float*)(AOh + 1048576);                // 8192x128 fp32

  unsigned short* WtQ2 = Wt + 49152;
  unsigned short* WtP1 = Wt + 98304;    unsigned short* WtP2 = Wt + 114688;
  unsigned short* WtMA1 = Wt + 131072;  unsigned short* WtMA2 = Wt + 163840;
  unsigned short* WtMB1a = Wt + 196608; unsigned short* WtMB1b = Wt + 212992;
  unsigned short* WtMB2a = Wt + 229376; unsigned short* WtMB2b = Wt + 245760;

  // 1) fused prep+conv+KV-proj (conv 528 | bevq 512 | wprep 36 | bias 1)
  k_prepconv<<<1077, 256, 0, stream>>>(aWqkv, aWp, Wma, Wmb, Wt,
      abqkv, biasP, gridp, Wbev, bbev, x, alng, alnb, Einv, Wcam, QPh,
      feat, gfp, bfp, Wfp, gfl, bfl, Wfl, Iinv, Wimg,
      KPh, KP2h, VPh, VP2h);

  // 2) stage-1 attention
  k_attn2<<<512, 256, 0, stream>>>(QPh, KPh, VPh, AOh, 6, 384);
  // 3) stage-1 tail: P+x-skip+LN+MA+gelu+MB -> Q1f, then fused q2-proj -> QPh
  k_tail<<<256, 256, 0, stream>>>(AOh, x, 1, WtP1, abp, png, pnb,
      WtMA1, WtMA1+16384, bma, WtMB1a, WtMB1b, bmb, Q1f,
      WtQ2, biasP+384, QSC, QPh,
      nullptr, nullptr, nullptr);
  // 4) stage-2 attention
  k_attn2<<<512, 256, 0, stream>>>(QPh, KP2h, VP2h, AOh, 1, 64);
  // 5) stage-2 tail (+final LN) -> out
  k_tail<<<256, 256, 0, stream>>>(AOh, Q1f, 3, WtP2, abp+128, png+128, pnb+128,
      WtMA2, WtMA2+16384, bma+256, WtMB2a, WtMB2b, bmb+128, nullptr,
      nullptr, nullptr, 0.f, nullptr,
      postg, postb, out);
}

// Round 10
// 240.938 us; speedup vs baseline: 1.0838x; 1.0078x over previous
//
#include <hip/hip_runtime.h>
#include <math.h>

// CrossViewSwapAttention forward. Round 21: tail occupancy split.
// k_tail rows/block 32 -> 16 (grid 256 -> 512): LDS 83 -> 58 KB => 2 blocks/CU,
// two serial tail chains co-resident per CU overlap each other's barrier/LDS
// stalls. No VGPR growth, no staging duplication (weights re-read from L2).
// k_prepconv / k_attn2 = R20 (R18 conv + attn Q-prefetch). 5 dispatches.
// B=2 N=6 H=W=64 FH=32 FW=88 DIM=128 HEADS=4 DH=32 QW=8x8 KW=4x11

typedef __attribute__((ext_vector_type(8))) short short8;
typedef __attribute__((ext_vector_type(4))) float f32x4;

__device__ __forceinline__ unsigned short f2bf(float f){
  union { float f; unsigned u; } v; v.f = f;
  unsigned r = v.u + 0x7FFF + ((v.u >> 16) & 1);   // RNE
  return (unsigned short)(r >> 16);
}
__device__ __forceinline__ float bf2f(unsigned short h){
  union { unsigned u; float f; } v; v.u = ((unsigned)h) << 16; return v.f;
}
__device__ __forceinline__ void store_bf16x8(unsigned short* p, const float* v){
  union { short8 s8; unsigned short u[8]; } u;
  #pragma unroll
  for (int i=0;i<8;i++) u.u[i] = f2bf(v[i]);
  *(short8*)p = u.s8;
}

__device__ __forceinline__ float gelu_erf(float x){
  float z = x * 0.70710678118654752f;
  float a = fabsf(z);
  float t = 1.0f / fmaf(0.3275911f, a, 1.0f);
  float p = t*(0.254829592f + t*(-0.284496736f + t*(1.421413741f +
            t*(-1.453152027f + t*1.061405429f))));
  float er = 1.0f - p*__expf(-a*a);
  er = copysignf(er, z);
  return 0.5f * x * (1.0f + er);
}

__device__ __forceinline__ size_t remap_kv(int tok, int mode){
  int bn = tok / 2816; int p = tok - bn*2816;
  int b = bn / 6, n = bn - b*6;
  int i = p / 88, j = p - i*88;
  int l, t;
  if (mode == 1){
    int jw = j / 11;
    l = (i >> 2)*8 + jw;
    t = n*44 + (i & 3)*11 + (j - jw*11);
  } else {
    l = (i & 7)*8 + (j & 7);
    t = n*44 + (i >> 3)*11 + (j >> 3);
  }
  return (size_t)((b*64 + l)*264 + t);
}

// == fused dispatch 1: conv(+geom+LN+dual KV proj) | bevq(+Q1) | wprep | bias
// grid: [0,528) conv, [528,1040) bevq, [1040,1076) wprep, [1076,1077) bias3
__global__ __launch_bounds__(256) void k_prepconv(
    const float* __restrict__ qkv, const float* __restrict__ wp,
    const float* __restrict__ wma, const float* __restrict__ wmb,
    unsigned short* __restrict__ Wt,
    const float* __restrict__ abqkv, float* __restrict__ biasP,
    const float* __restrict__ gridp, const float* __restrict__ Wbev,
    const float* __restrict__ bbev, const float* __restrict__ x,
    const float* __restrict__ lg, const float* __restrict__ lb,
    const float* __restrict__ Einv, const float* __restrict__ Wcam,
    unsigned short* __restrict__ QPh,
    const float* __restrict__ feat,
    const float* __restrict__ gfp, const float* __restrict__ bfp,
    const float* __restrict__ Wfp,
    const float* __restrict__ gfl, const float* __restrict__ bfl,
    const float* __restrict__ Wfl,
    const float* __restrict__ Iinv, const float* __restrict__ Wimg,
    unsigned short* __restrict__ KPh, unsigned short* __restrict__ KP2h,
    unsigned short* __restrict__ VPh, unsigned short* __restrict__ VP2h){
  constexpr int KP_ = 136;
  __shared__ unsigned short sW[128*KP_];
  __shared__ unsigned short sA[128*KP_];
  __shared__ __align__(16) float sMisc[2560];
  const int bid = blockIdx.x;
  const int tid = threadIdx.x;

  if (bid < 528){
    float* sg_  = sMisc;
    float* sb_  = sMisc + 128;
    float* sMean= sMisc + 256;
    float* sRstd= sMisc + 384;
    float* sRn  = sMisc + 512;
    float* sCE  = sMisc + 640;
    float4* sWI4= (float4*)(sMisc + 768);
    float* sIE  = sMisc + 1280;
    float* sB1  = sMisc + 1312;
    float* sB2  = sMisc + 1440;
    const int which = (bid >= 264);
    const int cbid = which ? bid - 264 : bid;
    const int m1 = which ? 2 : 1;
    const int m2 = which ? 5 : 4;
    const float* gg = which ? gfl : gfp;
    const float* bb = which ? bfl : bfp;
    const float* Wf = which ? Wfl : Wfp;
    unsigned short* Oa = which ? VPh : KPh;
    unsigned short* Ob = which ? VP2h : KP2h;
    const int base = cbid * 128;
    const int bn = base / 2816;
    const int pbase = base - bn*2816;
    if (tid < 128){ sg_[tid]=gg[tid]; sb_[tid]=bb[tid]; }
    if (!which){
      if (tid < 128){
        const float* E = Einv + bn*16;
        float4 wc = *(const float4*)(Wcam + tid*4);
        sCE[tid] = wc.x*E[3] + wc.y*E[7] + wc.z*E[11] + wc.w*E[15];
        sWI4[tid] = *(const float4*)(Wimg + tid*4);
      }
      if (tid < 25) sIE[tid] = (tid < 9) ? Iinv[bn*9 + tid] : Einv[bn*16 + (tid-9)];
    }
    for (int i = tid; i < 2048; i += 256){
      int n = i >> 4, k8 = (i & 15) << 3;
      const float* wsp = Wf + (size_t)n*128 + k8;
      float4 f0 = *(const float4*)wsp;
      float4 f1 = *(const float4*)(wsp+4);
      float v8[8] = {f0.x,f0.y,f0.z,f0.w,f1.x,f1.y,f1.z,f1.w};
      store_bf16x8(&sW[n*KP_ + k8], v8);
    }
    {
      int n = tid & 127, wsel = tid >> 7;
      int m = wsel ? m2 : m1;
      const float* W = qkv + m*16384;
      const float* lnb = lb + m*128;
      float s = abqkv[m*128 + n];
      for (int k=0;k<128;k++) s = fmaf(lnb[k], W[k*128 + n], s);
      (wsel ? sB2 : sB1)[n] = s;
    }
    const float RSQ = rsqrtf(1.0f + 1e-5f);
    {
      int prow = tid & 127, cseg = tid >> 7;
      int p = pbase + prow;
      const float* fb = feat + ((size_t)bn*128 + cseg*64)*2816 + p;
      #pragma unroll 8
      for (int i=0;i<64;i+=2){
        int c = cseg*64 + i;
        float t0 = fb[(size_t)i*2816] * RSQ;
        float t1 = fb[(size_t)(i+1)*2816] * RSQ;
        float y0 = fmaxf(fmaf(t0, sg_[c],   sb_[c]),   0.f);
        float y1 = fmaxf(fmaf(t1, sg_[c+1], sb_[c+1]), 0.f);
        unsigned u = (unsigned)f2bf(y0) | ((unsigned)f2bf(y1) << 16);
        *(unsigned*)&sA[prow*KP_ + c] = u;
      }
    }
    __syncthreads();
    const int lane = tid & 63, wv = tid >> 6;
    const int lane15 = lane & 15, quad = lane >> 4;
    const int n0 = wv * 32;
    const unsigned short* aptr = sA + lane15*KP_ + quad*8;
    const unsigned short* bptr = sW + (size_t)(n0 + lane15)*KP_ + quad*8;
    f32x4 acc[8][2];
    #pragma unroll
    for (int mt=0; mt<8; mt++){ acc[mt][0]=(f32x4)0.f; acc[mt][1]=(f32x4)0.f; }
    #pragma unroll
    for (int kk=0; kk<4; kk++){
      short8 af[8], bf2v[2];
      #pragma unroll
      for (int mt=0; mt<8; mt++) af[mt] = *(const short8*)(aptr + mt*16*KP_ + kk*32);
      bf2v[0] = *(const short8*)(bptr + kk*32);
      bf2v[1] = *(const short8*)(bptr + 16*KP_ + kk*32);
      #pragma unroll
      for (int mt=0; mt<8; mt++){
        acc[mt][0] = __builtin_amdgcn_mfma_f32_16x16x32_bf16(af[mt], bf2v[0], acc[mt][0], 0,0,0);
        acc[mt][1] = __builtin_amdgcn_mfma_f32_16x16x32_bf16(af[mt], bf2v[1], acc[mt][1], 0,0,0);
      }
    }
    __syncthreads();
    if (!which){
      const int r = tid >> 1, half = tid & 1;
      int p = pbase + r;
      int ii = p / 88, jj = p - ii*88;
      float xs = (float)jj * (480.0f/87.0f);
      float ys = (float)ii * (224.0f/31.0f);
      float c0 = sIE[0]*xs + sIE[1]*ys + sIE[2];
      float c1 = sIE[3]*xs + sIE[4]*ys + sIE[5];
      float c2 = sIE[6]*xs + sIE[7]*ys + sIE[8];
      float d0 = sIE[9]*c0  + sIE[10]*c1 + sIE[11]*c2 + sIE[12];
      float d1 = sIE[13]*c0 + sIE[14]*c1 + sIE[15]*c2 + sIE[16];
      float d2 = sIE[17]*c0 + sIE[18]*c1 + sIE[19]*c2 + sIE[20];
      float d3 = sIE[21]*c0 + sIE[22]*c1 + sIE[23]*c2 + sIE[24];
      float sq = 0.f;
      #pragma unroll 8
      for (int k=0;k<64;k++){
        int c = half*64 + k;
        float4 w = sWI4[c];
        float de = w.x*d0 + w.y*d1 + w.z*d2 + w.w*d3 - sCE[c];
        sA[r*KP_ + c] = f2bf(de);
        sq = fmaf(de, de, sq);
      }
      sq += __shfl_xor(sq, 1);
      if (half == 0) sRn[r] = 1.0f / fmaxf(sqrtf(sq), 1e-12f);
    }
    {
      const float* Wsrc = qkv + m1*16384;
      const float* gvv = lg + m1*128;
      for (int idx = tid; idx < 8192; idx += 256){
        int n = idx & 127, k2 = (idx >> 7) << 1;
        float v0 = Wsrc[(size_t)k2*128 + n]     * gvv[k2];
        float v1 = Wsrc[(size_t)(k2+1)*128 + n] * gvv[k2+1];
        *(unsigned*)&sW[n*KP_ + k2] = (unsigned)f2bf(v0) | ((unsigned)f2bf(v1) << 16);
      }
    }
    __syncthreads();
    #pragma unroll
    for (int mt=0; mt<8; mt++){
      #pragma unroll
      for (int nt=0; nt<2; nt++){
        int col = n0 + nt*16 + lane15;
        #pragma unroll
        for (int r4=0; r4<4; r4++){
          int row = mt*16 + quad*4 + r4;
          float v = acc[mt][nt][r4];
          if (!which) v += bf2f(sA[row*KP_ + col]) * sRn[row];   // + geom
          sA[row*KP_ + col] = f2bf(v);
        }
      }
    }
    __syncthreads();
    {
      int r = tid >> 1, part = tid & 1;
      float s=0.f, s2=0.f;
      #pragma unroll 8
      for (int k=0;k<64;k++){
        float v = bf2f(sA[r*KP_ + part*64 + k]);
        s += v; s2 = fmaf(v,v,s2);
      }
      s += __shfl_xor(s, 1); s2 += __shfl_xor(s2, 1);
      if (part == 0){
        float mean = s*(1.f/128.f);
        sMean[r] = mean;
        sRstd[r] = rsqrtf(fmaxf(s2*(1.f/128.f) - mean*mean, 0.f) + 1e-5f);
      }
    }
    __syncthreads();
    for (int i = tid; i < 2048; i += 256){
      int row = i >> 4, seg = i & 15;
      float mean = sMean[row], rstd = sRstd[row];
      union { short8 s; unsigned short u[8]; } t;
      t.s = *(const short8*)&sA[row*KP_ + seg*8];
      float v[8];
      #pragma unroll
      for (int k=0;k<8;k++) v[k] = (bf2f(t.u[k]) - mean)*rstd;
      store_bf16x8(&sA[row*KP_ + seg*8], v);
    }
    __syncthreads();
    #pragma unroll
    for (int mt=0; mt<8; mt++){ acc[mt][0]=(f32x4)0.f; acc[mt][1]=(f32x4)0.f; }
    #pragma unroll
    for (int kk=0; kk<4; kk++){
      short8 af[8], bf2v[2];
      #pragma unroll
      for (int mt=0; mt<8; mt++) af[mt] = *(const short8*)(aptr + mt*16*KP_ + kk*32);
      bf2v[0] = *(const short8*)(bptr + kk*32);
      bf2v[1] = *(const short8*)(bptr + 16*KP_ + kk*32);
      #pragma unroll
      for (int mt=0; mt<8; mt++){
        acc[mt][0] = __builtin_amdgcn_mfma_f32_16x16x32_bf16(af[mt], bf2v[0], acc[mt][0], 0,0,0);
        acc[mt][1] = __builtin_amdgcn_mfma_f32_16x16x32_bf16(af[mt], bf2v[1], acc[mt][1], 0,0,0);
      }
    }
    __syncthreads();
    #pragma unroll
    for (int mt=0; mt<8; mt++){
      #pragma unroll
      for (int nt=0; nt<2; nt++){
        int col = n0 + nt*16 + lane15;
        float bsv = sB1[col];
        #pragma unroll
        for (int r4=0; r4<4; r4++){
          int row = mt*16 + quad*4 + r4;
          sW[row*KP_ + col] = f2bf(acc[mt][nt][r4] + bsv);
        }
      }
    }
    __syncthreads();
    for (int i = tid; i < 2048; i += 256){
      int row = i >> 4, seg = i & 15;
      size_t orow = remap_kv(base + row, 1);
      *(short8*)(Oa + orow*128 + seg*8) = *(const short8*)&sW[row*KP_ + seg*8];
    }
    __syncthreads();
    {
      const float* Wsrc = qkv + m2*16384;
      const float* gvv = lg + m2*128;
      for (int idx = tid; idx < 8192; idx += 256){
        int n = idx & 127, k2 = (idx >> 7) << 1;
        float v0 = Wsrc[(size_t)k2*128 + n]     * gvv[k2];
        float v1 = Wsrc[(size_t)(k2+1)*128 + n] * gvv[k2+1];
        *(unsigned*)&sW[n*KP_ + k2] = (unsigned)f2bf(v0) | ((unsigned)f2bf(v1) << 16);
      }
    }
    __syncthreads();
    #pragma unroll
    for (int mt=0; mt<8; mt++){ acc[mt][0]=(f32x4)0.f; acc[mt][1]=(f32x4)0.f; }
    #pragma unroll
    for (int kk=0; kk<4; kk++){
      short8 af[8], bf2v[2];
      #pragma unroll
      for (int mt=0; mt<8; mt++) af[mt] = *(const short8*)(aptr + mt*16*KP_ + kk*32);
      bf2v[0] = *(const short8*)(bptr + kk*32);
      bf2v[1] = *(const short8*)(bptr + 16*KP_ + kk*32);
      #pragma unroll
      for (int mt=0; mt<8; mt++){
        acc[mt][0] = __builtin_amdgcn_mfma_f32_16x16x32_bf16(af[mt], bf2v[0], acc[mt][0], 0,0,0);
        acc[mt][1] = __builtin_amdgcn_mfma_f32_16x16x32_bf16(af[mt], bf2v[1], acc[mt][1], 0,0,0);
      }
    }
    __syncthreads();
    #pragma unroll
    for (int mt=0; mt<8; mt++){
      #pragma unroll
      for (int nt=0; nt<2; nt++){
        int col = n0 + nt*16 + lane15;
        float bsv = sB2[col];
        #pragma unroll
        for (int r4=0; r4<4; r4++){
          int row = mt*16 + quad*4 + r4;
          sA[row*KP_ + col] = f2bf(acc[mt][nt][r4] + bsv);
        }
      }
    }
    __syncthreads();
    for (int i = tid; i < 2048; i += 256){
      int row = i >> 4, seg = i & 15;
      size_t orow = remap_kv(base + row, 2);
      *(short8*)(Ob + orow*128 + seg*8) = *(const short8*)&sA[row*KP_ + seg*8];
    }
  } else if (bid < 1040){
    // ---- bevq + fused Q1 projection -> QPh (16 pixels/block) ----
    const float QSCALE = 0.17677669529663687f;
    float* sx = sMisc;
    int* rowoff = (int*)(sMisc + 2176);
    int bid2 = bid - 528;
    int b = bid2 >> 8; int pp0 = (bid2 & 255) << 4;
    // self-stage Q1 weight, 2 bf16 per dword write
    for (int idx = tid; idx < 8192; idx += 256){
      int n = idx & 127, k2 = (idx >> 7) << 1;
      float v0 = qkv[(size_t)k2*128 + n];
      float v1 = qkv[(size_t)(k2+1)*128 + n];
      *(unsigned*)&sW[n*KP_ + k2] = (unsigned)f2bf(v0) | ((unsigned)f2bf(v1) << 16);
    }
    {
      int cg = tid >> 4, px = tid & 15;
      #pragma unroll
      for (int i=0;i<8;i++){
        int c = cg + 16*i;
        sx[c*17 + px] = x[(size_t)b*524288 + (size_t)c*4096 + pp0 + px];
      }
    }
    if (tid < 16){
      int pix = pp0 + tid; int h = pix >> 6, w = pix & 63;
      int l = (h>>3)*8 + (w>>3); int tq = (h&7)*8 + (w&7);
      rowoff[tid] = (b*64 + l)*384 + tq;
    }
    __syncthreads();
    int xid = tid >> 4, part = tid & 15;
    int pix = pp0 + xid;
    float g0 = gridp[pix], g1 = gridp[4096 + pix];
    float we[8], xv[8];
    #pragma unroll
    for (int k=0;k<8;k++){
      int o = part*8 + k;
      we[k] = Wbev[o*2]*g0 + Wbev[o*2+1]*g1 + bbev[o];
      xv[k] = sx[(part*8+k)*17 + xid];
    }
    for (int n=0; n<6; n++){
      const float* E = Einv + (b*6+n)*16;
      float v[8]; float sq = 0.f;
      #pragma unroll
      for (int k=0;k<8;k++){
        int o = part*8 + k;
        const float* Wc = Wcam + o*4;
        float ce = Wc[0]*E[3] + Wc[1]*E[7] + Wc[2]*E[11] + Wc[3]*E[15];
        float vv = we[k] - ce;
        v[k] = vv; sq = fmaf(vv, vv, sq);
      }
      #pragma unroll
      for (int off=8; off>0; off>>=1) sq += __shfl_xor(sq, off, 16);
      float rn = 1.0f / fmaxf(sqrtf(sq), 1e-12f);
      float q[8]; float s=0.f, s2=0.f;
      #pragma unroll
      for (int k=0;k<8;k++){
        q[k] = fmaf(v[k], rn, xv[k]);
        s += q[k]; s2 = fmaf(q[k], q[k], s2);
      }
      #pragma unroll
      for (int off=8; off>0; off>>=1){ s += __shfl_xor(s, off, 16); s2 += __shfl_xor(s2, off, 16); }
      float mean = s*(1.f/128.f);
      float rstd = rsqrtf(fmaxf(s2*(1.f/128.f) - mean*mean, 0.f) + 1e-5f);
      float o8[8];
      #pragma unroll
      for (int k=0;k<8;k++){
        int c = part*8 + k;
        o8[k] = fmaf((q[k]-mean)*rstd, lg[c], lb[c]);
      }
      store_bf16x8(sA + (size_t)(n*16 + xid)*KP_ + part*8, o8);
    }
    __syncthreads();
    const int lane = tid & 63, wv = tid >> 6;
    const int lane15 = lane & 15, quad = lane >> 4;
    const int n0 = wv * 32;
    f32x4 acc[6][2];
    #pragma unroll
    for (int mt=0; mt<6; mt++){ acc[mt][0]=(f32x4)0.f; acc[mt][1]=(f32x4)0.f; }
    const unsigned short* aptr = sA + lane15*KP_ + quad*8;
    const unsigned short* bptr = sW + (size_t)(n0 + lane15)*KP_ + quad*8;
    #pragma unroll
    for (int kk=0; kk<4; kk++){
      short8 af[6], bf2v[2];
      #pragma unroll
      for (int mt=0; mt<6; mt++) af[mt] = *(const short8*)(aptr + mt*16*KP_ + kk*32);
      bf2v[0] = *(const short8*)(bptr + kk*32);
      bf2v[1] = *(const short8*)(bptr + 16*KP_ + kk*32);
      #pragma unroll
      for (int mt=0; mt<6; mt++){
        acc[mt][0] = __builtin_amdgcn_mfma_f32_16x16x32_bf16(af[mt], bf2v[0], acc[mt][0], 0,0,0);
        acc[mt][1] = __builtin_amdgcn_mfma_f32_16x16x32_bf16(af[mt], bf2v[1], acc[mt][1], 0,0,0);
      }
    }
    __syncthreads();
    #pragma unroll
    for (int nt=0; nt<2; nt++){
      int col = n0 + nt*16 + lane15;
      float bsv = abqkv[col];
      #pragma unroll
      for (int mt=0; mt<6; mt++){
        #pragma unroll
        for (int r4=0; r4<4; r4++){
          int row = mt*16 + quad*4 + r4;
          sA[row*KP_ + col] = f2bf((acc[mt][nt][r4] + bsv) * QSCALE);
        }
      }
    }
    __syncthreads();
    for (int i = tid; i < 1536; i += 256){
      int r = i >> 4, seg = i & 15;
      size_t grow = (size_t)rowoff[r & 15] + (r >> 4)*64;
      *(short8*)(QPh + grow*128 + seg*8) = *(const short8*)&sA[r*KP_ + seg*8];
    }
  } else if (bid < 1076){
    const int sel[9]  = {0, 1,1, 2,2, 3,3,3,3};
    const int soff[9] = {49152, 0,16384, 0,32768, 0,16384,32768,49152};
    const int doff[9] = {49152, 98304,114688, 131072,163840,
                         196608,212992,229376,245760};
    const int Ns[9]   = {128, 128,128, 256,256, 128,128,128,128};
    int bidw = bid - 1040;
    int sg = bidw >> 2, q = bidw & 3;
    const float* srcs[4] = {qkv, wp, wma, wmb};
    const float* src = srcs[sel[sg]] + soff[sg];
    unsigned short* dst = Wt + doff[sg];
    int K = 128, N = Ns[sg];
    int quarter = (K*N) >> 2;
    bool fold = (sg == 0);
    const float* gv = lg + 384;
    for (int idx = q*quarter + tid; idx < (q+1)*quarter; idx += 256){
      int n = idx / K, k = idx - n*K;
      float v = src[k*N + n];
      if (fold) v *= gv[k];
      dst[idx] = f2bf(v);
    }
  } else {
    if (tid < 128){
      int n = tid;
      const float* lnb = lb + 384;
      const float* W = qkv + 49152;
      float s = abqkv[384 + n];
      for (int k=0;k<128;k++) s = fmaf(lnb[k], W[k*128 + n], s);
      biasP[384 + n] = s;
    }
  }
}

// ---------------- fused tail, 16 rows/block (2 blocks/CU), T14 weights -----
__global__ __launch_bounds__(256) void k_tail(
    const unsigned short* __restrict__ AOh,
    const float* __restrict__ skipf, int skipmode,
    const unsigned short* __restrict__ WtP, const float* __restrict__ abp,
    const float* __restrict__ png, const float* __restrict__ pnb,
    const unsigned short* __restrict__ WtMAa, const unsigned short* __restrict__ WtMAb,
    const float* __restrict__ bma,
    const unsigned short* __restrict__ WtMBa, const unsigned short* __restrict__ WtMBb,
    const float* __restrict__ bmb,
    float* __restrict__ Q1out,
    const unsigned short* __restrict__ WtQ2, const float* __restrict__ q2bias,
    float q2scale, unsigned short* __restrict__ QPout,
    const float* __restrict__ postg, const float* __restrict__ postb,
    float* __restrict__ out){
  constexpr int KP_ = 136;
  __shared__ unsigned short sW[128*KP_];
  __shared__ unsigned short sX[16*KP_];
  __shared__ unsigned short sH1[16*KP_];
  __shared__ unsigned short sH2[16*KP_];
  __shared__ float sCUR[16*132];
  __shared__ float sbias[128];
  __shared__ float sg[128], sb2[128];
  __shared__ float sMean[16], sRstd[16];
  const int tid = threadIdx.x;
  const int base = blockIdx.x * 16;
  const int lane = tid & 63, wv = tid >> 6;
  const int lane15 = lane & 15, quad = lane >> 4;
  const int n0 = wv * 32;

  short8 wreg[8];
  auto stageLoad = [&](const unsigned short* Wp){
    #pragma unroll
    for (int i=0;i<8;i++){
      int idx = tid + i*256;
      int n = idx >> 4, k8 = (idx & 15) << 3;
      wreg[i] = *(const short8*)(Wp + (size_t)n*128 + k8);
    }
  };
  auto stageWrite = [&](){
    #pragma unroll
    for (int i=0;i<8;i++){
      int idx = tid + i*256;
      int n = idx >> 4, k8 = (idx & 15) << 3;
      *(short8*)&sW[n*KP_ + k8] = wreg[i];
    }
  };
  auto domfma = [&](const unsigned short* Asrc, f32x4 acc[2]){
    const unsigned short* aptr = Asrc + lane15*KP_ + quad*8;
    const unsigned short* bptr = sW + (size_t)(n0 + lane15)*KP_ + quad*8;
    #pragma unroll
    for (int kk=0; kk<4; kk++){
      short8 a0 = *(const short8*)(aptr + kk*32);
      short8 b0 = *(const short8*)(bptr + kk*32);
      short8 b1 = *(const short8*)(bptr + 16*KP_ + kk*32);
      acc[0] = __builtin_amdgcn_mfma_f32_16x16x32_bf16(a0,b0,acc[0],0,0,0);
      acc[1] = __builtin_amdgcn_mfma_f32_16x16x32_bf16(a0,b1,acc[1],0,0,0);
    }
  };

  // phase 0: W_P staged; attn output -> sX
  stageLoad(WtP);
  {
    const int r = tid >> 4, part = tid & 15;
    *(short8*)(sX + r*KP_ + part*8) =
      *(const short8*)(AOh + (size_t)(base+r)*128 + part*8);
  }
  if (tid < 128){ sbias[tid] = abp[tid]; sg[tid] = png[tid]; sb2[tid] = pnb[tid]; }
  stageWrite();
  __syncthreads();
  // phase 1: GEMM_P (W_MAa loads in flight underneath)
  stageLoad(WtMAa);
  {
    f32x4 acc[2];
    acc[0]=(f32x4)0.f; acc[1]=(f32x4)0.f;
    domfma(sX, acc);
    #pragma unroll
    for (int nt=0; nt<2; nt++){
      int col = n0 + nt*16 + lane15;
      float bsv = sbias[col];
      #pragma unroll
      for (int r4=0; r4<4; r4++){
        int row = quad*4 + r4;
        int rrow = base + row;
        float v = acc[nt][r4] + bsv;
        if (skipmode == 1){
          int bb = rrow >> 12, l = (rrow >> 6) & 63, pp = rrow & 63;
          int pix = (((l>>3)*8 + (pp>>3)) << 6) + (l&7)*8 + (pp&7);
          v += skipf[(size_t)bb*524288 + (size_t)col*4096 + pix];
        } else {
          v += skipf[(size_t)rrow*128 + col];
        }
        sCUR[row*132 + col] = v;
      }
    }
  }
  __syncthreads();
  // phase 2: write W_MAa; LN -> sX
  stageWrite();
  if (tid < 128) sbias[tid] = bma[tid];
  {
    const int r = tid >> 4, part = tid & 15;
    float v[8];
    #pragma unroll
    for (int k=0;k<8;k++) v[k] = sCUR[r*132 + part*8 + k];
    float s=0.f, s2=0.f;
    #pragma unroll
    for (int k=0;k<8;k++){ s += v[k]; s2 = fmaf(v[k],v[k],s2); }
    #pragma unroll
    for (int off=8; off>0; off>>=1){ s += __shfl_xor(s, off, 16); s2 += __shfl_xor(s2, off, 16); }
    float mean = s*(1.f/128.f);
    float rstd = rsqrtf(fmaxf(s2*(1.f/128.f) - mean*mean, 0.f) + 1e-5f);
    #pragma unroll
    for (int k=0;k<8;k++){
      int c = part*8 + k;
      v[k] = fmaf((v[k]-mean)*rstd, sg[c], sb2[c]);
    }
    store_bf16x8(sX + r*KP_ + part*8, v);
  }
  __syncthreads();
  // phase 3: GEMM_MAa -> sH1 (W_MAb loads in flight)
  stageLoad(WtMAb);
  {
    f32x4 acc[2];
    acc[0]=(f32x4)0.f; acc[1]=(f32x4)0.f;
    domfma(sX, acc);
    #pragma unroll
    for (int nt=0; nt<2; nt++){
      int col = n0 + nt*16 + lane15;
      float bsv = sbias[col];
      #pragma unroll
      for (int r4=0; r4<4; r4++){
        int row = quad*4 + r4;
        sH1[row*KP_ + col] = f2bf(gelu_erf(acc[nt][r4] + bsv));
      }
    }
  }
  __syncthreads();
  stageWrite();
  if (tid < 128) sbias[tid] = bma[128 + tid];
  __syncthreads();
  // phase 4: GEMM_MAb -> sH2 (W_MBa in flight)
  stageLoad(WtMBa);
  {
    f32x4 acc[2];
    acc[0]=(f32x4)0.f; acc[1]=(f32x4)0.f;
    domfma(sX, acc);
    #pragma unroll
    for (int nt=0; nt<2; nt++){
      int col = n0 + nt*16 + lane15;
      float bsv = sbias[col];
      #pragma unroll
      for (int r4=0; r4<4; r4++){
        int row = quad*4 + r4;
        sH2[row*KP_ + col] = f2bf(gelu_erf(acc[nt][r4] + bsv));
      }
    }
  }
  __syncthreads();
  stageWrite();
  if (tid < 128) sbias[tid] = bmb[tid];
  __syncthreads();
  // phase 5: GEMM_MBa(sH1) -> acc (W_MBb in flight)
  stageLoad(WtMBb);
  f32x4 acc[2];
  acc[0]=(f32x4)0.f; acc[1]=(f32x4)0.f;
  domfma(sH1, acc);
  __syncthreads();
  stageWrite();
  __syncthreads();
  // phase 6: GEMM_MBb(sH2) -> acc (+W_Q2 in flight for stage 1)
  if (WtQ2) stageLoad(WtQ2);
  domfma(sH2, acc);
  if (out == nullptr){
    // stage 1: Q1 fp32 + fused stage-2 q projection into QPout
    #pragma unroll
    for (int nt=0; nt<2; nt++){
      int col = n0 + nt*16 + lane15;
      float bsv = sbias[col];
      #pragma unroll
      for (int r4=0; r4<4; r4++){
        int row = quad*4 + r4;
        float v = acc[nt][r4] + bsv + sCUR[row*132 + col];
        sCUR[row*132 + col] = v;
        Q1out[(size_t)(base+row)*128 + col] = v;
      }
    }
    __syncthreads();
    {
      const int r = tid >> 4, part = tid & 15;
      float s=0.f, s2=0.f;
      #pragma unroll
      for (int k=0;k<8;k++){
        float v = sCUR[r*132 + part*8 + k];
        s += v; s2 = fmaf(v,v,s2);
      }
      #pragma unroll
      for (int off=8; off>0; off>>=1){ s += __shfl_xor(s, off, 16); s2 += __shfl_xor(s2, off, 16); }
      if (part == 0){
        float mean = s*(1.f/128.f);
        sMean[r] = mean;
        sRstd[r] = rsqrtf(fmaxf(s2*(1.f/128.f) - mean*mean, 0.f) + 1e-5f);
      }
    }
    __syncthreads();
    {
      const int r = tid >> 4, part = tid & 15;
      float mean = sMean[r], rstd = sRstd[r];
      float v[8];
      #pragma unroll
      for (int k=0;k<8;k++) v[k] = (sCUR[r*132 + part*8 + k] - mean)*rstd;
      store_bf16x8(sX + r*KP_ + part*8, v);
    }
    stageWrite();                         // W_Q2 -> sW
    if (tid < 128) sbias[tid] = q2bias[tid];
    __syncthreads();
    f32x4 a2[2];
    a2[0]=(f32x4)0.f; a2[1]=(f32x4)0.f;
    domfma(sX, a2);
    #pragma unroll
    for (int nt=0; nt<2; nt++){
      int col = n0 + nt*16 + lane15;
      float bsv = sbias[col];
      #pragma unroll
      for (int r4=0; r4<4; r4++){
        int row = quad*4 + r4;
        sH1[row*KP_ + col] = f2bf((a2[nt][r4] + bsv) * q2scale);
      }
    }
    __syncthreads();
    {
      int row = tid >> 4, seg = tid & 15;
      *(short8*)(QPout + (size_t)(base+row)*128 + seg*8) = *(const short8*)&sH1[row*KP_ + seg*8];
    }
  } else {
    float res[2][4];
    #pragma unroll
    for (int nt=0; nt<2; nt++){
      int col = n0 + nt*16 + lane15;
      float bsv = sbias[col];
      #pragma unroll
      for (int r4=0; r4<4; r4++){
        int row = quad*4 + r4;
        res[nt][r4] = acc[nt][r4] + bsv + sCUR[row*132 + col];
      }
    }
    __syncthreads();
    #pragma unroll
    for (int nt=0; nt<2; nt++){
      int col = n0 + nt*16 + lane15;
      #pragma unroll
      for (int r4=0; r4<4; r4++){
        int row = quad*4 + r4;
        sCUR[row*132 + col] = res[nt][r4];
      }
    }
    __syncthreads();
    {
      const int r = tid >> 4, part = tid & 15;
      float s=0.f, s2=0.f;
      #pragma unroll
      for (int k=0;k<8;k++){
        float v = sCUR[r*132 + part*8 + k];
        s += v; s2 = fmaf(v,v,s2);
      }
      #pragma unroll
      for (int off=8; off>0; off>>=1){ s += __shfl_xor(s, off, 16); s2 += __shfl_xor(s2, off, 16); }
      if (part == 0){
        float mean = s*(1.f/128.f);
        sMean[r] = mean;
        sRstd[r] = rsqrtf(fmaxf(s2*(1.f/128.f) - mean*mean, 0.f) + 1e-5f);
      }
    }
    __syncthreads();
    {
      int c = tid & 127, half = tid >> 7;
      int b = base >> 12, l = (base >> 6) & 63, p0 = base & 63;
      float go = postg[c], bo = postb[c];
      int p = p0 + half*8;
      int hrow = (l>>3)*8 + (p>>3);
      int w0 = (l&7)*8;
      float rr[8];
      #pragma unroll
      for (int j=0;j<8;j++){
        int row = half*8 + j;
        rr[j] = fmaf((sCUR[row*132 + c] - sMean[row])*sRstd[row], go, bo);
      }
      size_t obase = ((size_t)(b*128 + c))*4096 + (size_t)hrow*64 + w0;
      *(float4*)&out[obase]   = make_float4(rr[0],rr[1],rr[2],rr[3]);
      *(float4*)&out[obase+4] = make_float4(rr[4],rr[5],rr[6],rr[7]);
    }
  }
}

// ---------------- MFMA attention (pair-packed V staging, Q prefetch) --------
__global__ __launch_bounds__(256) void k_attn2(const unsigned short* __restrict__ QPh,
    const unsigned short* __restrict__ KPh, const unsigned short* __restrict__ VPh,
    unsigned short* __restrict__ AOh, int nrep, int nQ){
  __shared__ unsigned short Ksh[288*40];
  __shared__ unsigned short Vt[32*296];
  __shared__ unsigned short Psh[4*16*40];
  __shared__ float rs[4*16];
  int hd = blockIdx.x & 3; int bl = blockIdx.x >> 2;
  size_t kvbase = (size_t)bl*264;
  int tid = threadIdx.x;
  const int wv = tid >> 6, lane = tid & 63;
  const int lane15 = lane & 15, quad = lane >> 4;
  // T14: cam-0 Q fragment load issued before staging (hides under it)
  short8 qf_cur = *(const short8*)(QPh +
      (size_t)(bl*nQ + wv*16 + lane15)*128 + hd*32 + quad*8);
  for (int idx = tid; idx < 1056; idx += 256){
    int row = idx >> 2, seg = idx & 3;
    *(short8*)&Ksh[row*40 + seg*8] =
      *(const short8*)(KPh + (kvbase+row)*128 + hd*32 + seg*8);
  }
  for (int idx = tid; idx < 96; idx += 256){
    int row = 264 + (idx>>2), seg = idx & 3;
    short8 z = {0,0,0,0,0,0,0,0};
    *(short8*)&Ksh[row*40 + seg*8] = z;
  }
  for (int idx = tid; idx < 528; idx += 256){   // V transpose: 132 key-pairs x 4 segs
    int kp = idx >> 2, seg = idx & 3;
    union { short8 s; unsigned short u[8]; } a, b;
    a.s = *(const short8*)(VPh + (kvbase + 2*kp)*128 + hd*32 + seg*8);
    b.s = *(const short8*)(VPh + (kvbase + 2*kp + 1)*128 + hd*32 + seg*8);
    #pragma unroll
    for (int i=0;i<8;i++)
      *(unsigned*)&Vt[(seg*8+i)*296 + 2*kp] = (unsigned)a.u[i] | ((unsigned)b.u[i] << 16);
  }
  for (int idx = tid; idx < 384; idx += 256){
    int d = idx / 12, kp = 264 + (idx % 12)*2;
    *(unsigned*)&Vt[d*296 + kp] = 0u;
  }
  __syncthreads();
  unsigned short* Pw = Psh + wv*640;
  float* rsw = rs + wv*16;
  short8 vfrag[9][2];
  #pragma unroll
  for (int kc=0; kc<9; kc++){
    vfrag[kc][0] = *(const short8*)&Vt[(lane15)*296      + kc*32 + quad*8];
    vfrag[kc][1] = *(const short8*)&Vt[(16+lane15)*296   + kc*32 + quad*8];
  }
  f32x4 macc0 = (f32x4)0.f, macc1 = (f32x4)0.f;
  for (int cam = 0; cam < nrep; cam++){
    short8 qf = qf_cur;
    if (cam + 1 < nrep){                      // prefetch next cam's fragment
      int qrown = bl*nQ + ((cam+1)*4 + wv)*16 + lane15;
      qf_cur = *(const short8*)(QPh + (size_t)qrown*128 + hd*32 + quad*8);
    }
    f32x4 oa0 = (f32x4)0.f, oa1 = (f32x4)0.f;
    float rsum = 0.f;
    #pragma unroll
    for (int kc=0; kc<9; kc++){
      #pragma unroll
      for (int sub=0; sub<2; sub++){
        int kt = kc*2 + sub;
        short8 kf = *(const short8*)&Ksh[(kt*16 + lane15)*40 + quad*8];
        f32x4 st = __builtin_amdgcn_mfma_f32_16x16x32_bf16(kf, qf, (f32x4)0.f, 0,0,0);
        int kbase = kt*16 + quad*4;
        float e0 = (kbase+0 < 264) ? __expf(st[0]) : 0.f;
        float e1 = (kbase+1 < 264) ? __expf(st[1]) : 0.f;
        float e2 = (kbase+2 < 264) ? __expf(st[2]) : 0.f;
        float e3 = (kbase+3 < 264) ? __expf(st[3]) : 0.f;
        rsum += (e0+e1)+(e2+e3);
        uint2 pk;
        pk.x = (unsigned)f2bf(e0) | ((unsigned)f2bf(e1) << 16);
        pk.y = (unsigned)f2bf(e2) | ((unsigned)f2bf(e3) << 16);
        *(uint2*)&Pw[lane15*40 + sub*16 + quad*4] = pk;
      }
      short8 pf = *(const short8*)&Pw[lane15*40 + quad*8];
      oa0 = __builtin_amdgcn_mfma_f32_16x16x32_bf16(pf, vfrag[kc][0], oa0, 0,0,0);
      oa1 = __builtin_amdgcn_mfma_f32_16x16x32_bf16(pf, vfrag[kc][1], oa1, 0,0,0);
    }
    rsum += __shfl_xor(rsum, 16);
    rsum += __shfl_xor(rsum, 32);
    if (lane < 16) rsw[lane] = rsum;
    f32x4 rv = *(f32x4*)&rsw[quad*4];
    #pragma unroll
    for (int r=0;r<4;r++){
      float inv = 1.f / rv[r];
      macc0[r] = fmaf(oa0[r], inv, macc0[r]);
      macc1[r] = fmaf(oa1[r], inv, macc1[r]);
    }
  }
  float sc = (nrep == 6) ? (1.f/6.f) : 1.f;
  int pixb = wv*16 + quad*4;
  #pragma unroll
  for (int r=0;r<4;r++){
    size_t rowo = ((size_t)(bl*64 + pixb + r))*128 + hd*32;
    AOh[rowo + lane15]      = f2bf(macc0[r]*sc);
    AOh[rowo + 16 + lane15] = f2bf(macc1[r]*sc);
  }
}

extern "C" void kernel_launch(void* const* d_in, const int* in_sizes, int n_in,
                              void* d_out, int out_size, void* d_ws, size_t ws_size,
                              hipStream_t stream) {
  (void)in_sizes; (void)n_in; (void)out_size; (void)ws_size;
  const float* x     = (const float*)d_in[1];
  const float* gridp = (const float*)d_in[2];
  const float* feat  = (const float*)d_in[3];
  const float* Iinv  = (const float*)d_in[4];
  const float* Einv  = (const float*)d_in[5];
  const float* gfl   = (const float*)d_in[6];
  const float* bfl   = (const float*)d_in[7];
  const float* Wfl   = (const float*)d_in[8];
  const float* gfp   = (const float*)d_in[9];
  const float* bfp   = (const float*)d_in[10];
  const float* Wfp   = (const float*)d_in[11];
  const float* Wbev  = (const float*)d_in[12];
  const float* bbev  = (const float*)d_in[13];
  const float* Wimg  = (const float*)d_in[14];
  const float* Wcam  = (const float*)d_in[15];
  const float* alng  = (const float*)d_in[16];
  const float* alnb  = (const float*)d_in[17];
  const float* aWqkv = (const float*)d_in[18];
  const float* abqkv = (const float*)d_in[19];
  const float* aWp   = (const float*)d_in[20];
  const float* abp   = (const float*)d_in[21];
  const float* png   = (const float*)d_in[22];
  const float* pnb   = (const float*)d_in[23];
  const float* Wma   = (const float*)d_in[24];
  const float* bma   = (const float*)d_in[25];
  const float* Wmb   = (const float*)d_in[26];
  const float* bmb   = (const float*)d_in[27];
  const float* postg = (const float*)d_in[28];
  const float* postb = (const float*)d_in[29];
  float* out = (float*)d_out;
  float* ws  = (float*)d_ws;
  const float QSC = 0.17677669529663687f;

  float* biasP = ws;                                   // 768 fp32 (reserve 2048)
  unsigned short* Wt   = (unsigned short*)(ws + 2048);
  unsigned short* K1h  = (unsigned short*)(ws + 149504);   // (free slot)
  unsigned short* V1h  = K1h + 4325376;                    // (free slot)
  unsigned short* KPh  = V1h + 4325376;
  unsigned short* VPh  = KPh + 4325376;
  unsigned short* KP2h = VPh + 4325376;
  unsigned short* VP2h = KP2h + 4325376;
  unsigned short* QPh  = VP2h + 4325376;               // 49152x128
  unsigned short* Qbh  = QPh + 6291456;                // (unused, layout kept)
  unsigned short* AOh  = Qbh + 6291456;
  float* Q1f = (float*)(AOh + 1048576);                // 8192x128 fp32

  unsigned short* WtQ2 = Wt + 49152;
  unsigned short* WtP1 = Wt + 98304;    unsigned short* WtP2 = Wt + 114688;
  unsigned short* WtMA1 = Wt + 131072;  unsigned short* WtMA2 = Wt + 163840;
  unsigned short* WtMB1a = Wt + 196608; unsigned short* WtMB1b = Wt + 212992;
  unsigned short* WtMB2a = Wt + 229376; unsigned short* WtMB2b = Wt + 245760;

  // 1) fused prep+conv+KV-proj (conv 528 | bevq 512 | wprep 36 | bias 1)
  k_prepconv<<<1077, 256, 0, stream>>>(aWqkv, aWp, Wma, Wmb, Wt,
      abqkv, biasP, gridp, Wbev, bbev, x, alng, alnb, Einv, Wcam, QPh,
      feat, gfp, bfp, Wfp, gfl, bfl, Wfl, Iinv, Wimg,
      KPh, KP2h, VPh, VP2h);

  // 2) stage-1 attention
  k_attn2<<<512, 256, 0, stream>>>(QPh, KPh, VPh, AOh, 6, 384);
  // 3) stage-1 tail (16 rows/block): P+x-skip+LN+MA+gelu+MB -> Q1f, q2 -> QPh
  k_tail<<<512, 256, 0, stream>>>(AOh, x, 1, WtP1, abp, png, pnb,
      WtMA1, WtMA1+16384, bma, WtMB1a, WtMB1b, bmb, Q1f,
      WtQ2, biasP+384, QSC, QPh,
      nullptr, nullptr, nullptr);
  // 4) stage-2 attention
  k_attn2<<<512, 256, 0, stream>>>(QPh, KP2h, VP2h, AOh, 1, 64);
  // 5) stage-2 tail (16 rows/block, +final LN) -> out
  k_tail<<<512, 256, 0, stream>>>(AOh, Q1f, 3, WtP2, abp+128, png+128, pnb+128,
      WtMA2, WtMA2+16384, bma+256, WtMB2a, WtMB2b, bmb+128, nullptr,
      nullptr, nullptr, 0.f, nullptr,
      postg, postb, out);
}

// Round 11
// 238.241 us; speedup vs baseline: 1.0961x; 1.0113x over previous
//
#include <hip/hip_runtime.h>
#include <math.h>

// CrossViewSwapAttention forward. Round 22: attn wave-split (8 waves/block).
// k_attn2 -> 512 threads: waves = (q-quarter qw, half ch). nrep==6: each half
// computes 3 cameras fully (per-cam softmax self-contained), camera-mean
// combined once via LDS at the end. nrep==1: halves split the 18 kt chunks
// (softmax denom + PV linear in keys), partial oa/rsum combined before the
// single normalize. K/V staged ONCE per block (no duplication), no VGPR
// growth, LDS 47->53KB (3 blocks/CU capacity). Chain per block halves,
// waves/CU double. prepconv/k_tail = R21. 5 dispatches.
// B=2 N=6 H=W=64 FH=32 FW=88 DIM=128 HEADS=4 DH=32 QW=8x8 KW=4x11

typedef __attribute__((ext_vector_type(8))) short short8;
typedef __attribute__((ext_vector_type(4))) float f32x4;

__device__ __forceinline__ unsigned short f2bf(float f){
  union { float f; unsigned u; } v; v.f = f;
  unsigned r = v.u + 0x7FFF + ((v.u >> 16) & 1);   // RNE
  return (unsigned short)(r >> 16);
}
__device__ __forceinline__ float bf2f(unsigned short h){
  union { unsigned u; float f; } v; v.u = ((unsigned)h) << 16; return v.f;
}
__device__ __forceinline__ void store_bf16x8(unsigned short* p, const float* v){
  union { short8 s8; unsigned short u[8]; } u;
  #pragma unroll
  for (int i=0;i<8;i++) u.u[i] = f2bf(v[i]);
  *(short8*)p = u.s8;
}

__device__ __forceinline__ float gelu_erf(float x){
  float z = x * 0.70710678118654752f;
  float a = fabsf(z);
  float t = 1.0f / fmaf(0.3275911f, a, 1.0f);
  float p = t*(0.254829592f + t*(-0.284496736f + t*(1.421413741f +
            t*(-1.453152027f + t*1.061405429f))));
  float er = 1.0f - p*__expf(-a*a);
  er = copysignf(er, z);
  return 0.5f * x * (1.0f + er);
}

__device__ __forceinline__ size_t remap_kv(int tok, int mode){
  int bn = tok / 2816; int p = tok - bn*2816;
  int b = bn / 6, n = bn - b*6;
  int i = p / 88, j = p - i*88;
  int l, t;
  if (mode == 1){
    int jw = j / 11;
    l = (i >> 2)*8 + jw;
    t = n*44 + (i & 3)*11 + (j - jw*11);
  } else {
    l = (i & 7)*8 + (j & 7);
    t = n*44 + (i >> 3)*11 + (j >> 3);
  }
  return (size_t)((b*64 + l)*264 + t);
}

// == fused dispatch 1: conv(+geom+LN+dual KV proj) | bevq(+Q1) | wprep | bias
// grid: [0,528) conv, [528,1040) bevq, [1040,1076) wprep, [1076,1077) bias3
__global__ __launch_bounds__(256) void k_prepconv(
    const float* __restrict__ qkv, const float* __restrict__ wp,
    const float* __restrict__ wma, const float* __restrict__ wmb,
    unsigned short* __restrict__ Wt,
    const float* __restrict__ abqkv, float* __restrict__ biasP,
    const float* __restrict__ gridp, const float* __restrict__ Wbev,
    const float* __restrict__ bbev, const float* __restrict__ x,
    const float* __restrict__ lg, const float* __restrict__ lb,
    const float* __restrict__ Einv, const float* __restrict__ Wcam,
    unsigned short* __restrict__ QPh,
    const float* __restrict__ feat,
    const float* __restrict__ gfp, const float* __restrict__ bfp,
    const float* __restrict__ Wfp,
    const float* __restrict__ gfl, const float* __restrict__ bfl,
    const float* __restrict__ Wfl,
    const float* __restrict__ Iinv, const float* __restrict__ Wimg,
    unsigned short* __restrict__ KPh, unsigned short* __restrict__ KP2h,
    unsigned short* __restrict__ VPh, unsigned short* __restrict__ VP2h){
  constexpr int KP_ = 136;
  __shared__ unsigned short sW[128*KP_];
  __shared__ unsigned short sA[128*KP_];
  __shared__ __align__(16) float sMisc[2560];
  const int bid = blockIdx.x;
  const int tid = threadIdx.x;

  if (bid < 528){
    float* sg_  = sMisc;
    float* sb_  = sMisc + 128;
    float* sMean= sMisc + 256;
    float* sRstd= sMisc + 384;
    float* sRn  = sMisc + 512;
    float* sCE  = sMisc + 640;
    float4* sWI4= (float4*)(sMisc + 768);
    float* sIE  = sMisc + 1280;
    float* sB1  = sMisc + 1312;
    float* sB2  = sMisc + 1440;
    const int which = (bid >= 264);
    const int cbid = which ? bid - 264 : bid;
    const int m1 = which ? 2 : 1;
    const int m2 = which ? 5 : 4;
    const float* gg = which ? gfl : gfp;
    const float* bb = which ? bfl : bfp;
    const float* Wf = which ? Wfl : Wfp;
    unsigned short* Oa = which ? VPh : KPh;
    unsigned short* Ob = which ? VP2h : KP2h;
    const int base = cbid * 128;
    const int bn = base / 2816;
    const int pbase = base - bn*2816;
    if (tid < 128){ sg_[tid]=gg[tid]; sb_[tid]=bb[tid]; }
    if (!which){
      if (tid < 128){
        const float* E = Einv + bn*16;
        float4 wc = *(const float4*)(Wcam + tid*4);
        sCE[tid] = wc.x*E[3] + wc.y*E[7] + wc.z*E[11] + wc.w*E[15];
        sWI4[tid] = *(const float4*)(Wimg + tid*4);
      }
      if (tid < 25) sIE[tid] = (tid < 9) ? Iinv[bn*9 + tid] : Einv[bn*16 + (tid-9)];
    }
    for (int i = tid; i < 2048; i += 256){
      int n = i >> 4, k8 = (i & 15) << 3;
      const float* wsp = Wf + (size_t)n*128 + k8;
      float4 f0 = *(const float4*)wsp;
      float4 f1 = *(const float4*)(wsp+4);
      float v8[8] = {f0.x,f0.y,f0.z,f0.w,f1.x,f1.y,f1.z,f1.w};
      store_bf16x8(&sW[n*KP_ + k8], v8);
    }
    {
      int n = tid & 127, wsel = tid >> 7;
      int m = wsel ? m2 : m1;
      const float* W = qkv + m*16384;
      const float* lnb = lb + m*128;
      float s = abqkv[m*128 + n];
      for (int k=0;k<128;k++) s = fmaf(lnb[k], W[k*128 + n], s);
      (wsel ? sB2 : sB1)[n] = s;
    }
    const float RSQ = rsqrtf(1.0f + 1e-5f);
    {
      int prow = tid & 127, cseg = tid >> 7;
      int p = pbase + prow;
      const float* fb = feat + ((size_t)bn*128 + cseg*64)*2816 + p;
      #pragma unroll 8
      for (int i=0;i<64;i+=2){
        int c = cseg*64 + i;
        float t0 = fb[(size_t)i*2816] * RSQ;
        float t1 = fb[(size_t)(i+1)*2816] * RSQ;
        float y0 = fmaxf(fmaf(t0, sg_[c],   sb_[c]),   0.f);
        float y1 = fmaxf(fmaf(t1, sg_[c+1], sb_[c+1]), 0.f);
        unsigned u = (unsigned)f2bf(y0) | ((unsigned)f2bf(y1) << 16);
        *(unsigned*)&sA[prow*KP_ + c] = u;
      }
    }
    __syncthreads();
    const int lane = tid & 63, wv = tid >> 6;
    const int lane15 = lane & 15, quad = lane >> 4;
    const int n0 = wv * 32;
    const unsigned short* aptr = sA + lane15*KP_ + quad*8;
    const unsigned short* bptr = sW + (size_t)(n0 + lane15)*KP_ + quad*8;
    f32x4 acc[8][2];
    #pragma unroll
    for (int mt=0; mt<8; mt++){ acc[mt][0]=(f32x4)0.f; acc[mt][1]=(f32x4)0.f; }
    #pragma unroll
    for (int kk=0; kk<4; kk++){
      short8 af[8], bf2v[2];
      #pragma unroll
      for (int mt=0; mt<8; mt++) af[mt] = *(const short8*)(aptr + mt*16*KP_ + kk*32);
      bf2v[0] = *(const short8*)(bptr + kk*32);
      bf2v[1] = *(const short8*)(bptr + 16*KP_ + kk*32);
      #pragma unroll
      for (int mt=0; mt<8; mt++){
        acc[mt][0] = __builtin_amdgcn_mfma_f32_16x16x32_bf16(af[mt], bf2v[0], acc[mt][0], 0,0,0);
        acc[mt][1] = __builtin_amdgcn_mfma_f32_16x16x32_bf16(af[mt], bf2v[1], acc[mt][1], 0,0,0);
      }
    }
    __syncthreads();
    if (!which){
      const int r = tid >> 1, half = tid & 1;
      int p = pbase + r;
      int ii = p / 88, jj = p - ii*88;
      float xs = (float)jj * (480.0f/87.0f);
      float ys = (float)ii * (224.0f/31.0f);
      float c0 = sIE[0]*xs + sIE[1]*ys + sIE[2];
      float c1 = sIE[3]*xs + sIE[4]*ys + sIE[5];
      float c2 = sIE[6]*xs + sIE[7]*ys + sIE[8];
      float d0 = sIE[9]*c0  + sIE[10]*c1 + sIE[11]*c2 + sIE[12];
      float d1 = sIE[13]*c0 + sIE[14]*c1 + sIE[15]*c2 + sIE[16];
      float d2 = sIE[17]*c0 + sIE[18]*c1 + sIE[19]*c2 + sIE[20];
      float d3 = sIE[21]*c0 + sIE[22]*c1 + sIE[23]*c2 + sIE[24];
      float sq = 0.f;
      #pragma unroll 8
      for (int k=0;k<64;k++){
        int c = half*64 + k;
        float4 w = sWI4[c];
        float de = w.x*d0 + w.y*d1 + w.z*d2 + w.w*d3 - sCE[c];
        sA[r*KP_ + c] = f2bf(de);
        sq = fmaf(de, de, sq);
      }
      sq += __shfl_xor(sq, 1);
      if (half == 0) sRn[r] = 1.0f / fmaxf(sqrtf(sq), 1e-12f);
    }
    {
      const float* Wsrc = qkv + m1*16384;
      const float* gvv = lg + m1*128;
      for (int idx = tid; idx < 8192; idx += 256){
        int n = idx & 127, k2 = (idx >> 7) << 1;
        float v0 = Wsrc[(size_t)k2*128 + n]     * gvv[k2];
        float v1 = Wsrc[(size_t)(k2+1)*128 + n] * gvv[k2+1];
        *(unsigned*)&sW[n*KP_ + k2] = (unsigned)f2bf(v0) | ((unsigned)f2bf(v1) << 16);
      }
    }
    __syncthreads();
    #pragma unroll
    for (int mt=0; mt<8; mt++){
      #pragma unroll
      for (int nt=0; nt<2; nt++){
        int col = n0 + nt*16 + lane15;
        #pragma unroll
        for (int r4=0; r4<4; r4++){
          int row = mt*16 + quad*4 + r4;
          float v = acc[mt][nt][r4];
          if (!which) v += bf2f(sA[row*KP_ + col]) * sRn[row];   // + geom
          sA[row*KP_ + col] = f2bf(v);
        }
      }
    }
    __syncthreads();
    {
      int r = tid >> 1, part = tid & 1;
      float s=0.f, s2=0.f;
      #pragma unroll 8
      for (int k=0;k<64;k++){
        float v = bf2f(sA[r*KP_ + part*64 + k]);
        s += v; s2 = fmaf(v,v,s2);
      }
      s += __shfl_xor(s, 1); s2 += __shfl_xor(s2, 1);
      if (part == 0){
        float mean = s*(1.f/128.f);
        sMean[r] = mean;
        sRstd[r] = rsqrtf(fmaxf(s2*(1.f/128.f) - mean*mean, 0.f) + 1e-5f);
      }
    }
    __syncthreads();
    for (int i = tid; i < 2048; i += 256){
      int row = i >> 4, seg = i & 15;
      float mean = sMean[row], rstd = sRstd[row];
      union { short8 s; unsigned short u[8]; } t;
      t.s = *(const short8*)&sA[row*KP_ + seg*8];
      float v[8];
      #pragma unroll
      for (int k=0;k<8;k++) v[k] = (bf2f(t.u[k]) - mean)*rstd;
      store_bf16x8(&sA[row*KP_ + seg*8], v);
    }
    __syncthreads();
    #pragma unroll
    for (int mt=0; mt<8; mt++){ acc[mt][0]=(f32x4)0.f; acc[mt][1]=(f32x4)0.f; }
    #pragma unroll
    for (int kk=0; kk<4; kk++){
      short8 af[8], bf2v[2];
      #pragma unroll
      for (int mt=0; mt<8; mt++) af[mt] = *(const short8*)(aptr + mt*16*KP_ + kk*32);
      bf2v[0] = *(const short8*)(bptr + kk*32);
      bf2v[1] = *(const short8*)(bptr + 16*KP_ + kk*32);
      #pragma unroll
      for (int mt=0; mt<8; mt++){
        acc[mt][0] = __builtin_amdgcn_mfma_f32_16x16x32_bf16(af[mt], bf2v[0], acc[mt][0], 0,0,0);
        acc[mt][1] = __builtin_amdgcn_mfma_f32_16x16x32_bf16(af[mt], bf2v[1], acc[mt][1], 0,0,0);
      }
    }
    __syncthreads();
    #pragma unroll
    for (int mt=0; mt<8; mt++){
      #pragma unroll
      for (int nt=0; nt<2; nt++){
        int col = n0 + nt*16 + lane15;
        float bsv = sB1[col];
        #pragma unroll
        for (int r4=0; r4<4; r4++){
          int row = mt*16 + quad*4 + r4;
          sW[row*KP_ + col] = f2bf(acc[mt][nt][r4] + bsv);
        }
      }
    }
    __syncthreads();
    for (int i = tid; i < 2048; i += 256){
      int row = i >> 4, seg = i & 15;
      size_t orow = remap_kv(base + row, 1);
      *(short8*)(Oa + orow*128 + seg*8) = *(const short8*)&sW[row*KP_ + seg*8];
    }
    __syncthreads();
    {
      const float* Wsrc = qkv + m2*16384;
      const float* gvv = lg + m2*128;
      for (int idx = tid; idx < 8192; idx += 256){
        int n = idx & 127, k2 = (idx >> 7) << 1;
        float v0 = Wsrc[(size_t)k2*128 + n]     * gvv[k2];
        float v1 = Wsrc[(size_t)(k2+1)*128 + n] * gvv[k2+1];
        *(unsigned*)&sW[n*KP_ + k2] = (unsigned)f2bf(v0) | ((unsigned)f2bf(v1) << 16);
      }
    }
    __syncthreads();
    #pragma unroll
    for (int mt=0; mt<8; mt++){ acc[mt][0]=(f32x4)0.f; acc[mt][1]=(f32x4)0.f; }
    #pragma unroll
    for (int kk=0; kk<4; kk++){
      short8 af[8], bf2v[2];
      #pragma unroll
      for (int mt=0; mt<8; mt++) af[mt] = *(const short8*)(aptr + mt*16*KP_ + kk*32);
      bf2v[0] = *(const short8*)(bptr + kk*32);
      bf2v[1] = *(const short8*)(bptr + 16*KP_ + kk*32);
      #pragma unroll
      for (int mt=0; mt<8; mt++){
        acc[mt][0] = __builtin_amdgcn_mfma_f32_16x16x32_bf16(af[mt], bf2v[0], acc[mt][0], 0,0,0);
        acc[mt][1] = __builtin_amdgcn_mfma_f32_16x16x32_bf16(af[mt], bf2v[1], acc[mt][1], 0,0,0);
      }
    }
    __syncthreads();
    #pragma unroll
    for (int mt=0; mt<8; mt++){
      #pragma unroll
      for (int nt=0; nt<2; nt++){
        int col = n0 + nt*16 + lane15;
        float bsv = sB2[col];
        #pragma unroll
        for (int r4=0; r4<4; r4++){
          int row = mt*16 + quad*4 + r4;
          sA[row*KP_ + col] = f2bf(acc[mt][nt][r4] + bsv);
        }
      }
    }
    __syncthreads();
    for (int i = tid; i < 2048; i += 256){
      int row = i >> 4, seg = i & 15;
      size_t orow = remap_kv(base + row, 2);
      *(short8*)(Ob + orow*128 + seg*8) = *(const short8*)&sA[row*KP_ + seg*8];
    }
  } else if (bid < 1040){
    // ---- bevq + fused Q1 projection -> QPh (16 pixels/block) ----
    const float QSCALE = 0.17677669529663687f;
    float* sx = sMisc;
    int* rowoff = (int*)(sMisc + 2176);
    int bid2 = bid - 528;
    int b = bid2 >> 8; int pp0 = (bid2 & 255) << 4;
    // self-stage Q1 weight, 2 bf16 per dword write
    for (int idx = tid; idx < 8192; idx += 256){
      int n = idx & 127, k2 = (idx >> 7) << 1;
      float v0 = qkv[(size_t)k2*128 + n];
      float v1 = qkv[(size_t)(k2+1)*128 + n];
      *(unsigned*)&sW[n*KP_ + k2] = (unsigned)f2bf(v0) | ((unsigned)f2bf(v1) << 16);
    }
    {
      int cg = tid >> 4, px = tid & 15;
      #pragma unroll
      for (int i=0;i<8;i++){
        int c = cg + 16*i;
        sx[c*17 + px] = x[(size_t)b*524288 + (size_t)c*4096 + pp0 + px];
      }
    }
    if (tid < 16){
      int pix = pp0 + tid; int h = pix >> 6, w = pix & 63;
      int l = (h>>3)*8 + (w>>3); int tq = (h&7)*8 + (w&7);
      rowoff[tid] = (b*64 + l)*384 + tq;
    }
    __syncthreads();
    int xid = tid >> 4, part = tid & 15;
    int pix = pp0 + xid;
    float g0 = gridp[pix], g1 = gridp[4096 + pix];
    float we[8], xv[8];
    #pragma unroll
    for (int k=0;k<8;k++){
      int o = part*8 + k;
      we[k] = Wbev[o*2]*g0 + Wbev[o*2+1]*g1 + bbev[o];
      xv[k] = sx[(part*8+k)*17 + xid];
    }
    for (int n=0; n<6; n++){
      const float* E = Einv + (b*6+n)*16;
      float v[8]; float sq = 0.f;
      #pragma unroll
      for (int k=0;k<8;k++){
        int o = part*8 + k;
        const float* Wc = Wcam + o*4;
        float ce = Wc[0]*E[3] + Wc[1]*E[7] + Wc[2]*E[11] + Wc[3]*E[15];
        float vv = we[k] - ce;
        v[k] = vv; sq = fmaf(vv, vv, sq);
      }
      #pragma unroll
      for (int off=8; off>0; off>>=1) sq += __shfl_xor(sq, off, 16);
      float rn = 1.0f / fmaxf(sqrtf(sq), 1e-12f);
      float q[8]; float s=0.f, s2=0.f;
      #pragma unroll
      for (int k=0;k<8;k++){
        q[k] = fmaf(v[k], rn, xv[k]);
        s += q[k]; s2 = fmaf(q[k], q[k], s2);
      }
      #pragma unroll
      for (int off=8; off>0; off>>=1){ s += __shfl_xor(s, off, 16); s2 += __shfl_xor(s2, off, 16); }
      float mean = s*(1.f/128.f);
      float rstd = rsqrtf(fmaxf(s2*(1.f/128.f) - mean*mean, 0.f) + 1e-5f);
      float o8[8];
      #pragma unroll
      for (int k=0;k<8;k++){
        int c = part*8 + k;
        o8[k] = fmaf((q[k]-mean)*rstd, lg[c], lb[c]);
      }
      store_bf16x8(sA + (size_t)(n*16 + xid)*KP_ + part*8, o8);
    }
    __syncthreads();
    const int lane = tid & 63, wv = tid >> 6;
    const int lane15 = lane & 15, quad = lane >> 4;
    const int n0 = wv * 32;
    f32x4 acc[6][2];
    #pragma unroll
    for (int mt=0; mt<6; mt++){ acc[mt][0]=(f32x4)0.f; acc[mt][1]=(f32x4)0.f; }
    const unsigned short* aptr = sA + lane15*KP_ + quad*8;
    const unsigned short* bptr = sW + (size_t)(n0 + lane15)*KP_ + quad*8;
    #pragma unroll
    for (int kk=0; kk<4; kk++){
      short8 af[6], bf2v[2];
      #pragma unroll
      for (int mt=0; mt<6; mt++) af[mt] = *(const short8*)(aptr + mt*16*KP_ + kk*32);
      bf2v[0] = *(const short8*)(bptr + kk*32);
      bf2v[1] = *(const short8*)(bptr + 16*KP_ + kk*32);
      #pragma unroll
      for (int mt=0; mt<6; mt++){
        acc[mt][0] = __builtin_amdgcn_mfma_f32_16x16x32_bf16(af[mt], bf2v[0], acc[mt][0], 0,0,0);
        acc[mt][1] = __builtin_amdgcn_mfma_f32_16x16x32_bf16(af[mt], bf2v[1], acc[mt][1], 0,0,0);
      }
    }
    __syncthreads();
    #pragma unroll
    for (int nt=0; nt<2; nt++){
      int col = n0 + nt*16 + lane15;
      float bsv = abqkv[col];
      #pragma unroll
      for (int mt=0; mt<6; mt++){
        #pragma unroll
        for (int r4=0; r4<4; r4++){
          int row = mt*16 + quad*4 + r4;
          sA[row*KP_ + col] = f2bf((acc[mt][nt][r4] + bsv) * QSCALE);
        }
      }
    }
    __syncthreads();
    for (int i = tid; i < 1536; i += 256){
      int r = i >> 4, seg = i & 15;
      size_t grow = (size_t)rowoff[r & 15] + (r >> 4)*64;
      *(short8*)(QPh + grow*128 + seg*8) = *(const short8*)&sA[r*KP_ + seg*8];
    }
  } else if (bid < 1076){
    const int sel[9]  = {0, 1,1, 2,2, 3,3,3,3};
    const int soff[9] = {49152, 0,16384, 0,32768, 0,16384,32768,49152};
    const int doff[9] = {49152, 98304,114688, 131072,163840,
                         196608,212992,229376,245760};
    const int Ns[9]   = {128, 128,128, 256,256, 128,128,128,128};
    int bidw = bid - 1040;
    int sg = bidw >> 2, q = bidw & 3;
    const float* srcs[4] = {qkv, wp, wma, wmb};
    const float* src = srcs[sel[sg]] + soff[sg];
    unsigned short* dst = Wt + doff[sg];
    int K = 128, N = Ns[sg];
    int quarter = (K*N) >> 2;
    bool fold = (sg == 0);
    const float* gv = lg + 384;
    for (int idx = q*quarter + tid; idx < (q+1)*quarter; idx += 256){
      int n = idx / K, k = idx - n*K;
      float v = src[k*N + n];
      if (fold) v *= gv[k];
      dst[idx] = f2bf(v);
    }
  } else {
    if (tid < 128){
      int n = tid;
      const float* lnb = lb + 384;
      const float* W = qkv + 49152;
      float s = abqkv[384 + n];
      for (int k=0;k<128;k++) s = fmaf(lnb[k], W[k*128 + n], s);
      biasP[384 + n] = s;
    }
  }
}

// ---------------- fused tail, 16 rows/block (2 blocks/CU), T14 weights -----
__global__ __launch_bounds__(256) void k_tail(
    const unsigned short* __restrict__ AOh,
    const float* __restrict__ skipf, int skipmode,
    const unsigned short* __restrict__ WtP, const float* __restrict__ abp,
    const float* __restrict__ png, const float* __restrict__ pnb,
    const unsigned short* __restrict__ WtMAa, const unsigned short* __restrict__ WtMAb,
    const float* __restrict__ bma,
    const unsigned short* __restrict__ WtMBa, const unsigned short* __restrict__ WtMBb,
    const float* __restrict__ bmb,
    float* __restrict__ Q1out,
    const unsigned short* __restrict__ WtQ2, const float* __restrict__ q2bias,
    float q2scale, unsigned short* __restrict__ QPout,
    const float* __restrict__ postg, const float* __restrict__ postb,
    float* __restrict__ out){
  constexpr int KP_ = 136;
  __shared__ unsigned short sW[128*KP_];
  __shared__ unsigned short sX[16*KP_];
  __shared__ unsigned short sH1[16*KP_];
  __shared__ unsigned short sH2[16*KP_];
  __shared__ float sCUR[16*132];
  __shared__ float sbias[128];
  __shared__ float sg[128], sb2[128];
  __shared__ float sMean[16], sRstd[16];
  const int tid = threadIdx.x;
  const int base = blockIdx.x * 16;
  const int lane = tid & 63, wv = tid >> 6;
  const int lane15 = lane & 15, quad = lane >> 4;
  const int n0 = wv * 32;

  short8 wreg[8];
  auto stageLoad = [&](const unsigned short* Wp){
    #pragma unroll
    for (int i=0;i<8;i++){
      int idx = tid + i*256;
      int n = idx >> 4, k8 = (idx & 15) << 3;
      wreg[i] = *(const short8*)(Wp + (size_t)n*128 + k8);
    }
  };
  auto stageWrite = [&](){
    #pragma unroll
    for (int i=0;i<8;i++){
      int idx = tid + i*256;
      int n = idx >> 4, k8 = (idx & 15) << 3;
      *(short8*)&sW[n*KP_ + k8] = wreg[i];
    }
  };
  auto domfma = [&](const unsigned short* Asrc, f32x4 acc[2]){
    const unsigned short* aptr = Asrc + lane15*KP_ + quad*8;
    const unsigned short* bptr = sW + (size_t)(n0 + lane15)*KP_ + quad*8;
    #pragma unroll
    for (int kk=0; kk<4; kk++){
      short8 a0 = *(const short8*)(aptr + kk*32);
      short8 b0 = *(const short8*)(bptr + kk*32);
      short8 b1 = *(const short8*)(bptr + 16*KP_ + kk*32);
      acc[0] = __builtin_amdgcn_mfma_f32_16x16x32_bf16(a0,b0,acc[0],0,0,0);
      acc[1] = __builtin_amdgcn_mfma_f32_16x16x32_bf16(a0,b1,acc[1],0,0,0);
    }
  };

  // phase 0: W_P staged; attn output -> sX
  stageLoad(WtP);
  {
    const int r = tid >> 4, part = tid & 15;
    *(short8*)(sX + r*KP_ + part*8) =
      *(const short8*)(AOh + (size_t)(base+r)*128 + part*8);
  }
  if (tid < 128){ sbias[tid] = abp[tid]; sg[tid] = png[tid]; sb2[tid] = pnb[tid]; }
  stageWrite();
  __syncthreads();
  // phase 1: GEMM_P (W_MAa loads in flight underneath)
  stageLoad(WtMAa);
  {
    f32x4 acc[2];
    acc[0]=(f32x4)0.f; acc[1]=(f32x4)0.f;
    domfma(sX, acc);
    #pragma unroll
    for (int nt=0; nt<2; nt++){
      int col = n0 + nt*16 + lane15;
      float bsv = sbias[col];
      #pragma unroll
      for (int r4=0; r4<4; r4++){
        int row = quad*4 + r4;
        int rrow = base + row;
        float v = acc[nt][r4] + bsv;
        if (skipmode == 1){
          int bb = rrow >> 12, l = (rrow >> 6) & 63, pp = rrow & 63;
          int pix = (((l>>3)*8 + (pp>>3)) << 6) + (l&7)*8 + (pp&7);
          v += skipf[(size_t)bb*524288 + (size_t)col*4096 + pix];
        } else {
          v += skipf[(size_t)rrow*128 + col];
        }
        sCUR[row*132 + col] = v;
      }
    }
  }
  __syncthreads();
  // phase 2: write W_MAa; LN -> sX
  stageWrite();
  if (tid < 128) sbias[tid] = bma[tid];
  {
    const int r = tid >> 4, part = tid & 15;
    float v[8];
    #pragma unroll
    for (int k=0;k<8;k++) v[k] = sCUR[r*132 + part*8 + k];
    float s=0.f, s2=0.f;
    #pragma unroll
    for (int k=0;k<8;k++){ s += v[k]; s2 = fmaf(v[k],v[k],s2); }
    #pragma unroll
    for (int off=8; off>0; off>>=1){ s += __shfl_xor(s, off, 16); s2 += __shfl_xor(s2, off, 16); }
    float mean = s*(1.f/128.f);
    float rstd = rsqrtf(fmaxf(s2*(1.f/128.f) - mean*mean, 0.f) + 1e-5f);
    #pragma unroll
    for (int k=0;k<8;k++){
      int c = part*8 + k;
      v[k] = fmaf((v[k]-mean)*rstd, sg[c], sb2[c]);
    }
    store_bf16x8(sX + r*KP_ + part*8, v);
  }
  __syncthreads();
  // phase 3: GEMM_MAa -> sH1 (W_MAb loads in flight)
  stageLoad(WtMAb);
  {
    f32x4 acc[2];
    acc[0]=(f32x4)0.f; acc[1]=(f32x4)0.f;
    domfma(sX, acc);
    #pragma unroll
    for (int nt=0; nt<2; nt++){
      int col = n0 + nt*16 + lane15;
      float bsv = sbias[col];
      #pragma unroll
      for (int r4=0; r4<4; r4++){
        int row = quad*4 + r4;
        sH1[row*KP_ + col] = f2bf(gelu_erf(acc[nt][r4] + bsv));
      }
    }
  }
  __syncthreads();
  stageWrite();
  if (tid < 128) sbias[tid] = bma[128 + tid];
  __syncthreads();
  // phase 4: GEMM_MAb -> sH2 (W_MBa in flight)
  stageLoad(WtMBa);
  {
    f32x4 acc[2];
    acc[0]=(f32x4)0.f; acc[1]=(f32x4)0.f;
    domfma(sX, acc);
    #pragma unroll
    for (int nt=0; nt<2; nt++){
      int col = n0 + nt*16 + lane15;
      float bsv = sbias[col];
      #pragma unroll
      for (int r4=0; r4<4; r4++){
        int row = quad*4 + r4;
        sH2[row*KP_ + col] = f2bf(gelu_erf(acc[nt][r4] + bsv));
      }
    }
  }
  __syncthreads();
  stageWrite();
  if (tid < 128) sbias[tid] = bmb[tid];
  __syncthreads();
  // phase 5: GEMM_MBa(sH1) -> acc (W_MBb in flight)
  stageLoad(WtMBb);
  f32x4 acc[2];
  acc[0]=(f32x4)0.f; acc[1]=(f32x4)0.f;
  domfma(sH1, acc);
  __syncthreads();
  stageWrite();
  __syncthreads();
  // phase 6: GEMM_MBb(sH2) -> acc (+W_Q2 in flight for stage 1)
  if (WtQ2) stageLoad(WtQ2);
  domfma(sH2, acc);
  if (out == nullptr){
    // stage 1: Q1 fp32 + fused stage-2 q projection into QPout
    #pragma unroll
    for (int nt=0; nt<2; nt++){
      int col = n0 + nt*16 + lane15;
      float bsv = sbias[col];
      #pragma unroll
      for (int r4=0; r4<4; r4++){
        int row = quad*4 + r4;
        float v = acc[nt][r4] + bsv + sCUR[row*132 + col];
        sCUR[row*132 + col] = v;
        Q1out[(size_t)(base+row)*128 + col] = v;
      }
    }
    __syncthreads();
    {
      const int r = tid >> 4, part = tid & 15;
      float s=0.f, s2=0.f;
      #pragma unroll
      for (int k=0;k<8;k++){
        float v = sCUR[r*132 + part*8 + k];
        s += v; s2 = fmaf(v,v,s2);
      }
      #pragma unroll
      for (int off=8; off>0; off>>=1){ s += __shfl_xor(s, off, 16); s2 += __shfl_xor(s2, off, 16); }
      if (part == 0){
        float mean = s*(1.f/128.f);
        sMean[r] = mean;
        sRstd[r] = rsqrtf(fmaxf(s2*(1.f/128.f) - mean*mean, 0.f) + 1e-5f);
      }
    }
    __syncthreads();
    {
      const int r = tid >> 4, part = tid & 15;
      float mean = sMean[r], rstd = sRstd[r];
      float v[8];
      #pragma unroll
      for (int k=0;k<8;k++) v[k] = (sCUR[r*132 + part*8 + k] - mean)*rstd;
      store_bf16x8(sX + r*KP_ + part*8, v);
    }
    stageWrite();                         // W_Q2 -> sW
    if (tid < 128) sbias[tid] = q2bias[tid];
    __syncthreads();
    f32x4 a2[2];
    a2[0]=(f32x4)0.f; a2[1]=(f32x4)0.f;
    domfma(sX, a2);
    #pragma unroll
    for (int nt=0; nt<2; nt++){
      int col = n0 + nt*16 + lane15;
      float bsv = sbias[col];
      #pragma unroll
      for (int r4=0; r4<4; r4++){
        int row = quad*4 + r4;
        sH1[row*KP_ + col] = f2bf((a2[nt][r4] + bsv) * q2scale);
      }
    }
    __syncthreads();
    {
      int row = tid >> 4, seg = tid & 15;
      *(short8*)(QPout + (size_t)(base+row)*128 + seg*8) = *(const short8*)&sH1[row*KP_ + seg*8];
    }
  } else {
    float res[2][4];
    #pragma unroll
    for (int nt=0; nt<2; nt++){
      int col = n0 + nt*16 + lane15;
      float bsv = sbias[col];
      #pragma unroll
      for (int r4=0; r4<4; r4++){
        int row = quad*4 + r4;
        res[nt][r4] = acc[nt][r4] + bsv + sCUR[row*132 + col];
      }
    }
    __syncthreads();
    #pragma unroll
    for (int nt=0; nt<2; nt++){
      int col = n0 + nt*16 + lane15;
      #pragma unroll
      for (int r4=0; r4<4; r4++){
        int row = quad*4 + r4;
        sCUR[row*132 + col] = res[nt][r4];
      }
    }
    __syncthreads();
    {
      const int r = tid >> 4, part = tid & 15;
      float s=0.f, s2=0.f;
      #pragma unroll
      for (int k=0;k<8;k++){
        float v = sCUR[r*132 + part*8 + k];
        s += v; s2 = fmaf(v,v,s2);
      }
      #pragma unroll
      for (int off=8; off>0; off>>=1){ s += __shfl_xor(s, off, 16); s2 += __shfl_xor(s2, off, 16); }
      if (part == 0){
        float mean = s*(1.f/128.f);
        sMean[r] = mean;
        sRstd[r] = rsqrtf(fmaxf(s2*(1.f/128.f) - mean*mean, 0.f) + 1e-5f);
      }
    }
    __syncthreads();
    {
      int c = tid & 127, half = tid >> 7;
      int b = base >> 12, l = (base >> 6) & 63, p0 = base & 63;
      float go = postg[c], bo = postb[c];
      int p = p0 + half*8;
      int hrow = (l>>3)*8 + (p>>3);
      int w0 = (l&7)*8;
      float rr[8];
      #pragma unroll
      for (int j=0;j<8;j++){
        int row = half*8 + j;
        rr[j] = fmaf((sCUR[row*132 + c] - sMean[row])*sRstd[row], go, bo);
      }
      size_t obase = ((size_t)(b*128 + c))*4096 + (size_t)hrow*64 + w0;
      *(float4*)&out[obase]   = make_float4(rr[0],rr[1],rr[2],rr[3]);
      *(float4*)&out[obase+4] = make_float4(rr[4],rr[5],rr[6],rr[7]);
    }
  }
}

// ---------------- MFMA attention, 8-wave split ------------------------------
// wave = (qw = q-quarter, ch = half). nrep==6: ch handles cams [ch*3,ch*3+3),
// per-cam softmax complete, camera-sum combined via LDS at end. nrep==1:
// ch splits kc chunks 5/4; partial oa/rsum combined before normalize.
#define KC_BODY(kcv) { \
  _Pragma("unroll") \
  for (int sub=0; sub<2; sub++){ \
    int kt = (kcv)*2 + sub; \
    short8 kf = *(const short8*)&Ksh[(kt*16 + lane15)*40 + quad*8]; \
    f32x4 st = __builtin_amdgcn_mfma_f32_16x16x32_bf16(kf, qf, (f32x4)0.f, 0,0,0); \
    int kbase = kt*16 + quad*4; \
    float e0 = (kbase+0 < 264) ? __expf(st[0]) : 0.f; \
    float e1 = (kbase+1 < 264) ? __expf(st[1]) : 0.f; \
    float e2 = (kbase+2 < 264) ? __expf(st[2]) : 0.f; \
    float e3 = (kbase+3 < 264) ? __expf(st[3]) : 0.f; \
    rsum += (e0+e1)+(e2+e3); \
    uint2 pk; \
    pk.x = (unsigned)f2bf(e0) | ((unsigned)f2bf(e1) << 16); \
    pk.y = (unsigned)f2bf(e2) | ((unsigned)f2bf(e3) << 16); \
    *(uint2*)&Pw[lane15*40 + sub*16 + quad*4] = pk; \
  } \
  short8 pf = *(const short8*)&Pw[lane15*40 + quad*8]; \
  oa0 = __builtin_amdgcn_mfma_f32_16x16x32_bf16(pf, vfrag[kcv][0], oa0, 0,0,0); \
  oa1 = __builtin_amdgcn_mfma_f32_16x16x32_bf16(pf, vfrag[kcv][1], oa1, 0,0,0); \
}

__global__ __launch_bounds__(512) void k_attn2(const unsigned short* __restrict__ QPh,
    const unsigned short* __restrict__ KPh, const unsigned short* __restrict__ VPh,
    unsigned short* __restrict__ AOh, int nrep, int nQ){
  __shared__ unsigned short Ksh[288*40];
  __shared__ unsigned short Vt[32*296];
  __shared__ unsigned short Psh[8*16*40];   // per-wave P scratch; reused as combine buf
  __shared__ float rs[8*16];
  int hd = blockIdx.x & 3; int bl = blockIdx.x >> 2;
  size_t kvbase = (size_t)bl*264;
  int tid = threadIdx.x;
  const int wv = tid >> 6, lane = tid & 63;
  const int qw = wv & 3, ch = wv >> 2;
  const int lane15 = lane & 15, quad = lane >> 4;
  // Q prefetch: first cam of this wave's set (hides under staging)
  const int cam_first = (nrep == 6) ? ch*3 : 0;
  short8 qf_cur = *(const short8*)(QPh +
      (size_t)(bl*nQ + (cam_first*4 + qw)*16 + lane15)*128 + hd*32 + quad*8);
  for (int idx = tid; idx < 1056; idx += 512){
    int row = idx >> 2, seg = idx & 3;
    *(short8*)&Ksh[row*40 + seg*8] =
      *(const short8*)(KPh + (kvbase+row)*128 + hd*32 + seg*8);
  }
  for (int idx = tid; idx < 96; idx += 512){
    int row = 264 + (idx>>2), seg = idx & 3;
    short8 z = {0,0,0,0,0,0,0,0};
    *(short8*)&Ksh[row*40 + seg*8] = z;
  }
  for (int idx = tid; idx < 528; idx += 512){   // V transpose: 132 key-pairs x 4 segs
    int kp = idx >> 2, seg = idx & 3;
    union { short8 s; unsigned short u[8]; } a, b;
    a.s = *(const short8*)(VPh + (kvbase + 2*kp)*128 + hd*32 + seg*8);
    b.s = *(const short8*)(VPh + (kvbase + 2*kp + 1)*128 + hd*32 + seg*8);
    #pragma unroll
    for (int i=0;i<8;i++)
      *(unsigned*)&Vt[(seg*8+i)*296 + 2*kp] = (unsigned)a.u[i] | ((unsigned)b.u[i] << 16);
  }
  for (int idx = tid; idx < 384; idx += 512){
    int d = idx / 12, kp = 264 + (idx % 12)*2;
    *(unsigned*)&Vt[d*296 + kp] = 0u;
  }
  __syncthreads();
  unsigned short* Pw = Psh + wv*640;
  float* rsw = rs + wv*16;
  short8 vfrag[9][2];
  #pragma unroll
  for (int kc=0; kc<9; kc++){
    vfrag[kc][0] = *(const short8*)&Vt[(lane15)*296      + kc*32 + quad*8];
    vfrag[kc][1] = *(const short8*)&Vt[(16+lane15)*296   + kc*32 + quad*8];
  }
  float* red = (float*)Psh;                      // 8KB combine area (post-barrier)
  if (nrep == 6){
    f32x4 macc0 = (f32x4)0.f, macc1 = (f32x4)0.f;
    #pragma unroll
    for (int ci = 0; ci < 3; ci++){
      int cam = ch*3 + ci;
      short8 qf = qf_cur;
      if (ci + 1 < 3){                           // prefetch next cam in my set
        int qrown = bl*nQ + ((cam+1)*4 + qw)*16 + lane15;
        qf_cur = *(const short8*)(QPh + (size_t)qrown*128 + hd*32 + quad*8);
      }
      f32x4 oa0 = (f32x4)0.f, oa1 = (f32x4)0.f;
      float rsum = 0.f;
      #pragma unroll
      for (int kc=0; kc<9; kc++) KC_BODY(kc)
      rsum += __shfl_xor(rsum, 16);
      rsum += __shfl_xor(rsum, 32);
      if (lane < 16) rsw[lane] = rsum;
      f32x4 rv = *(f32x4*)&rsw[quad*4];
      #pragma unroll
      for (int r=0;r<4;r++){
        float inv = 1.f / rv[r];
        macc0[r] = fmaf(oa0[r], inv, macc0[r]);
        macc1[r] = fmaf(oa1[r], inv, macc1[r]);
      }
    }
    __syncthreads();                             // all Pw reads done
    if (ch == 1){
      float* dst = red + (size_t)(qw*64 + lane)*8;
      #pragma unroll
      for (int r=0;r<4;r++){ dst[r] = macc0[r]; dst[4+r] = macc1[r]; }
    }
    __syncthreads();
    if (ch == 0){
      const float* src = red + (size_t)(qw*64 + lane)*8;
      int pixb = qw*16 + quad*4;
      #pragma unroll
      for (int r=0;r<4;r++){
        size_t rowo = ((size_t)(bl*64 + pixb + r))*128 + hd*32;
        AOh[rowo + lane15]      = f2bf((macc0[r] + src[r])   * (1.f/6.f));
        AOh[rowo + 16 + lane15] = f2bf((macc1[r] + src[4+r]) * (1.f/6.f));
      }
    }
  } else {
    short8 qf = qf_cur;
    f32x4 oa0 = (f32x4)0.f, oa1 = (f32x4)0.f;
    float rsum = 0.f;
    if (ch == 0){
      #pragma unroll
      for (int kc=0; kc<5; kc++) KC_BODY(kc)
    } else {
      #pragma unroll
      for (int kc=5; kc<9; kc++) KC_BODY(kc)
    }
    rsum += __shfl_xor(rsum, 16);
    rsum += __shfl_xor(rsum, 32);
    if (lane < 16) rsw[lane] = rsum;
    __syncthreads();                             // rs halves visible; Pw reads done
    if (ch == 1){
      float* dst = red + (size_t)(qw*64 + lane)*8;
      #pragma unroll
      for (int r=0;r<4;r++){ dst[r] = oa0[r]; dst[4+r] = oa1[r]; }
    }
    __syncthreads();
    if (ch == 0){
      const float* src = red + (size_t)(qw*64 + lane)*8;
      f32x4 rv0 = *(f32x4*)&rs[qw*16 + quad*4];
      f32x4 rv1 = *(f32x4*)&rs[(4+qw)*16 + quad*4];
      int pixb = qw*16 + quad*4;
      #pragma unroll
      for (int r=0;r<4;r++){
        float inv = 1.f / (rv0[r] + rv1[r]);
        size_t rowo = ((size_t)(bl*64 + pixb + r))*128 + hd*32;
        AOh[rowo + lane15]      = f2bf((oa0[r] + src[r])   * inv);
        AOh[rowo + 16 + lane15] = f2bf((oa1[r] + src[4+r]) * inv);
      }
    }
  }
}

extern "C" void kernel_launch(void* const* d_in, const int* in_sizes, int n_in,
                              void* d_out, int out_size, void* d_ws, size_t ws_size,
                              hipStream_t stream) {
  (void)in_sizes; (void)n_in; (void)out_size; (void)ws_size;
  const float* x     = (const float*)d_in[1];
  const float* gridp = (const float*)d_in[2];
  const float* feat  = (const float*)d_in[3];
  const float* Iinv  = (const float*)d_in[4];
  const float* Einv  = (const float*)d_in[5];
  const float* gfl   = (const float*)d_in[6];
  const float* bfl   = (const float*)d_in[7];
  const float* Wfl   = (const float*)d_in[8];
  const float* gfp   = (const float*)d_in[9];
  const float* bfp   = (const float*)d_in[10];
  const float* Wfp   = (const float*)d_in[11];
  const float* Wbev  = (const float*)d_in[12];
  const float* bbev  = (const float*)d_in[13];
  const float* Wimg  = (const float*)d_in[14];
  const float* Wcam  = (const float*)d_in[15];
  const float* alng  = (const float*)d_in[16];
  const float* alnb  = (const float*)d_in[17];
  const float* aWqkv = (const float*)d_in[18];
  const float* abqkv = (const float*)d_in[19];
  const float* aWp   = (const float*)d_in[20];
  const float* abp   = (const float*)d_in[21];
  const float* png   = (const float*)d_in[22];
  const float* pnb   = (const float*)d_in[23];
  const float* Wma   = (const float*)d_in[24];
  const float* bma   = (const float*)d_in[25];
  const float* Wmb   = (const float*)d_in[26];
  const float* bmb   = (const float*)d_in[27];
  const float* postg = (const float*)d_in[28];
  const float* postb = (const float*)d_in[29];
  float* out = (float*)d_out;
  float* ws  = (float*)d_ws;
  const float QSC = 0.17677669529663687f;

  float* biasP = ws;                                   // 768 fp32 (reserve 2048)
  unsigned short* Wt   = (unsigned short*)(ws + 2048);
  unsigned short* K1h  = (unsigned short*)(ws + 149504);   // (free slot)
  unsigned short* V1h  = K1h + 4325376;                    // (free slot)
  unsigned short* KPh  = V1h + 4325376;
  unsigned short* VPh  = KPh + 4325376;
  unsigned short* KP2h = VPh + 4325376;
  unsigned short* VP2h = KP2h + 4325376;
  unsigned short* QPh  = VP2h + 4325376;               // 49152x128
  unsigned short* Qbh  = QPh + 6291456;                // (unused, layout kept)
  unsigned short* AOh  = Qbh + 6291456;
  float* Q1f = (float*)(AOh + 1048576);                // 8192x128 fp32

  unsigned short* WtQ2 = Wt + 49152;
  unsigned short* WtP1 = Wt + 98304;    unsigned short* WtP2 = Wt + 114688;
  unsigned short* WtMA1 = Wt + 131072;  unsigned short* WtMA2 = Wt + 163840;
  unsigned short* WtMB1a = Wt + 196608; unsigned short* WtMB1b = Wt + 212992;
  unsigned short* WtMB2a = Wt + 229376; unsigned short* WtMB2b = Wt + 245760;

  // 1) fused prep+conv+KV-proj (conv 528 | bevq 512 | wprep 36 | bias 1)
  k_prepconv<<<1077, 256, 0, stream>>>(aWqkv, aWp, Wma, Wmb, Wt,
      abqkv, biasP, gridp, Wbev, bbev, x, alng, alnb, Einv, Wcam, QPh,
      feat, gfp, bfp, Wfp, gfl, bfl, Wfl, Iinv, Wimg,
      KPh, KP2h, VPh, VP2h);

  // 2) stage-1 attention (8-wave cam-split)
  k_attn2<<<512, 512, 0, stream>>>(QPh, KPh, VPh, AOh, 6, 384);
  // 3) stage-1 tail (16 rows/block): P+x-skip+LN+MA+gelu+MB -> Q1f, q2 -> QPh
  k_tail<<<512, 256, 0, stream>>>(AOh, x, 1, WtP1, abp, png, pnb,
      WtMA1, WtMA1+16384, bma, WtMB1a, WtMB1b, bmb, Q1f,
      WtQ2, biasP+384, QSC, QPh,
      nullptr, nullptr, nullptr);
  // 4) stage-2 attention (8-wave kc-split)
  k_attn2<<<512, 512, 0, stream>>>(QPh, KP2h, VP2h, AOh, 1, 64);
  // 5) stage-2 tail (16 rows/block, +final LN) -> out
  k_tail<<<512, 256, 0, stream>>>(AOh, Q1f, 3, WtP2, abp+128, png+128, pnb+128,
      WtMA2, WtMA2+16384, bma+256, WtMB2a, WtMB2b, bmb+128, nullptr,
      nullptr, nullptr, 0.f, nullptr,
      postg, postb, out);
}